// Round 2
// baseline (6001.157 us; speedup 1.0000x reference)
//
#include <hip/hip_runtime.h>
#include <math.h>
#include <stdint.h>

typedef unsigned long long u64;

// ---------------- problem constants ----------------
constexpr int L  = 4096;
constexpr int C  = 384;
constexpr int C3 = 1152;
constexpr int HD = 48;
constexpr int NCL = 16;
constexpr int KNN = 10;
constexpr int KM_ITERS = 50;

// ---------------- workspace layout (bytes) ----------------
// fz (double[L][C], 12.58MB) is dead before qkv (float[L][C3], 18.87MB) is
// written -> they share one region.
constexpr size_t AL(size_t x){ return (x + 255) & ~size_t(255); }
constexpr size_t OFF_AB    = 0;                                       // union fz/qkv
constexpr size_t OFF_FZ    = OFF_AB;                                  // double [L][C]
constexpr size_t OFF_QKV   = OFF_AB;                                  // float [L][C3]
constexpr size_t OFF_ATTN  = AL(OFF_AB    + sizeof(float)*L*C3);      // float [L][C]
constexpr size_t OFF_H     = AL(OFF_ATTN  + sizeof(float)*L*C);       // float [L][C]
constexpr size_t OFF_CZ    = AL(OFF_H     + sizeof(float)*L*C);       // double [L][2]
constexpr size_t OFF_SQ    = AL(OFF_CZ    + sizeof(double)*L*2);      // double [L]
constexpr size_t OFF_CM    = AL(OFF_SQ    + sizeof(double)*L);        // double [C]
constexpr size_t OFF_CD    = AL(OFF_CM    + sizeof(double)*C);        // double [C]
constexpr size_t OFF_CCM   = AL(OFF_CD    + sizeof(double)*C);        // double [2]
constexpr size_t OFF_CCD   = AL(OFF_CCM   + sizeof(double)*2);        // double [2]
constexpr size_t OFF_SP    = AL(OFF_CCD   + sizeof(double)*2);        // double [512]
constexpr size_t OFF_SP2   = AL(OFF_SP    + sizeof(double)*512);      // double [512]
constexpr size_t OFF_CONST = AL(OFF_SP2   + sizeof(double)*512);      // double [8]: sigma,w0,w1,meandist
constexpr size_t OFF_KNN   = AL(OFF_CONST + sizeof(double)*8);        // double [L][KNN]
constexpr size_t OFF_LBL   = AL(OFF_KNN   + sizeof(double)*L*KNN);    // int [L]
constexpr size_t OFF_ORD   = AL(OFF_LBL   + sizeof(int)*L);           // int [L]
constexpr size_t OFF_OFFS  = AL(OFF_ORD   + sizeof(int)*L);           // int [17]
constexpr size_t OFF_REPS  = AL(OFF_OFFS  + sizeof(int)*32);          // float [16][C]
constexpr size_t OFF_GQKV  = AL(OFF_REPS  + sizeof(float)*NCL*C);     // float [16][C3]
constexpr size_t OFF_GATT  = AL(OFF_GQKV  + sizeof(float)*NCL*C3);    // float [16][C]
constexpr size_t OFF_GREP  = AL(OFF_GATT  + sizeof(float)*NCL*C);     // float [16][C]
constexpr size_t OFF_RMEAN = AL(OFF_GREP  + sizeof(float)*NCL*C);     // float [C]
constexpr size_t OFF_CTRL  = AL(OFF_RMEAN + sizeof(float)*C);         // kmeans control (memset 0)

struct KCtrl {
  u64 sums[3][160];   // int64 fixed-point (2^52) center sums, 3-slot rotation
  int cnt[3][16];
  int chg[3];
  int bar;
};
constexpr size_t CTRL_BYTES = sizeof(KCtrl);
constexpr double FXS = 4503599627370496.0;   // 2^52

#define SCOPE_AGENT __HIP_MEMORY_SCOPE_AGENT

// =============== K1: per-column mean / std(ddof=1), fp64 ===============
__global__ void k_colstats(const float* __restrict__ x, const float* __restrict__ coords, char* ws){
  double* colm = (double*)(ws + OFF_CM);
  double* cold = (double*)(ws + OFF_CD);
  double* ccm  = (double*)(ws + OFF_CCM);
  double* ccd  = (double*)(ws + OFF_CCD);
  int b = blockIdx.x, t = threadIdx.x;
  __shared__ double red[256];
  __shared__ double muS[16];
  if (b < 24) {
    int co = t & 15, rg = t >> 4;
    int col = b*16 + co;
    double s = 0.0;
    for (int r = rg; r < L; r += 16) s += (double)x[r*C + col];
    red[t] = s; __syncthreads();
    for (int w = 8; w >= 1; w >>= 1){ if (rg < w) red[t] += red[t + w*16]; __syncthreads(); }
    if (rg == 0) muS[co] = red[co] / 4096.0;
    __syncthreads();
    double mu = muS[co];
    double ss = 0.0;
    for (int r = rg; r < L; r += 16){ double d = (double)x[r*C + col] - mu; ss += d * d; }
    red[t] = ss; __syncthreads();
    for (int w = 8; w >= 1; w >>= 1){ if (rg < w) red[t] += red[t + w*16]; __syncthreads(); }
    if (rg == 0){ colm[col] = mu; cold[col] = sqrt(red[co] / 4095.0) + 1e-6; }
  } else {
    int co = t & 1, rg = t >> 1;   // 128 row-groups x 2 cols
    double s = 0.0;
    for (int r = rg; r < L; r += 128) s += (double)coords[r*2 + co];
    red[t] = s; __syncthreads();
    for (int w = 64; w >= 1; w >>= 1){ if (rg < w) red[t] += red[t + w*2]; __syncthreads(); }
    if (rg == 0) muS[co] = red[co] / 4096.0;
    __syncthreads();
    double mu = muS[co];
    double ss = 0.0;
    for (int r = rg; r < L; r += 128){ double d = (double)coords[r*2 + co] - mu; ss += d * d; }
    red[t] = ss; __syncthreads();
    for (int w = 64; w >= 1; w >>= 1){ if (rg < w) red[t] += red[t + w*2]; __syncthreads(); }
    if (rg == 0){ ccm[co] = mu; ccd[co] = sqrt(red[co] / 4095.0) + 1e-6; }
  }
}

// =============== K2: fz (z-score + row L2-normalize), cz, sq — fp64 ===============
__global__ void k_normalize(const float* __restrict__ x, const float* __restrict__ coords, char* ws){
  double* fz = (double*)(ws + OFF_FZ);
  double* cz = (double*)(ws + OFF_CZ);
  double* sq = (double*)(ws + OFF_SQ);
  const double* colm = (const double*)(ws + OFF_CM);
  const double* cold = (const double*)(ws + OFF_CD);
  const double* ccm  = (const double*)(ws + OFF_CCM);
  const double* ccd  = (const double*)(ws + OFF_CCD);
  int i = blockIdx.x, t = threadIdx.x; // 128 threads
  double z[3];
  #pragma unroll
  for (int q = 0; q < 3; q++){ int c = t + q*128; z[q] = ((double)x[i*C + c] - colm[c]) / cold[c]; }
  __shared__ double red[128];
  __shared__ double nrmS;
  double s = z[0]*z[0] + z[1]*z[1] + z[2]*z[2];
  red[t] = s; __syncthreads();
  for (int w = 64; w >= 1; w >>= 1){ if (t < w) red[t] += red[t + w]; __syncthreads(); }
  if (t == 0){ double n = sqrt(red[0]); nrmS = n > 1e-12 ? n : 1e-12; }
  __syncthreads();
  double n = nrmS;
  #pragma unroll
  for (int q = 0; q < 3; q++){ int c = t + q*128; fz[(size_t)i*C + c] = z[q] / n; }
  if (t == 0){
    #pragma clang fp contract(off)
    double c0 = ((double)coords[i*2 + 0] - ccm[0]) / ccd[0];
    double c1 = ((double)coords[i*2 + 1] - ccm[1]) / ccd[1];
    cz[i*2 + 0] = c0; cz[i*2 + 1] = c1;
    double p0 = c0*c0; double p1 = c1*c1;
    sq[i] = p0 + p1;
  }
}

// =============== K3a/K3b/K3c/K4: sigma = std(dist, ddof=1), two-pass fp64 ===============
__global__ void k_sigsum(char* ws){
  const double* cz = (const double*)(ws + OFF_CZ);
  const double* sq = (const double*)(ws + OFF_SQ);
  double* sp = (double*)(ws + OFF_SP);
  int b = blockIdx.x, t = threadIdx.x; // 512 x 256
  double s = 0.0;
  const long long total = (long long)L * (long long)L;
  for (long long idx = (long long)b*256 + t; idx < total; idx += (long long)512*256){
    #pragma clang fp contract(off)
    int i = (int)(idx >> 12), j = (int)(idx & 4095);
    double p0 = cz[i*2] * cz[j*2];
    double p1 = cz[i*2+1] * cz[j*2+1];
    double g = p0 + p1;
    double d2 = (sq[i] + sq[j]) - 2.0*g;
    d2 = d2 > 0.0 ? d2 : 0.0;
    s += sqrt(d2);
  }
  __shared__ double r1[256];
  r1[t] = s; __syncthreads();
  for (int w = 128; w >= 1; w >>= 1){ if (t < w) r1[t] += r1[t+w]; __syncthreads(); }
  if (t == 0) sp[b] = r1[0];
}

__global__ void k_sigmean(char* ws){
  const double* sp = (const double*)(ws + OFF_SP);
  double* cst = (double*)(ws + OFF_CONST);
  int t = threadIdx.x; // 256
  __shared__ double r1[256];
  double a = sp[t] + sp[256 + t];
  r1[t] = a; __syncthreads();
  for (int w = 128; w >= 1; w >>= 1){ if (t < w) r1[t] += r1[t+w]; __syncthreads(); }
  if (t == 0) cst[3] = r1[0] / ((double)L * (double)L);
}

__global__ void k_sigvar(char* ws){
  const double* cz = (const double*)(ws + OFF_CZ);
  const double* sq = (const double*)(ws + OFF_SQ);
  const double* cst = (const double*)(ws + OFF_CONST);
  double* sp2 = (double*)(ws + OFF_SP2);
  int b = blockIdx.x, t = threadIdx.x; // 512 x 256
  double mean = cst[3];
  double s = 0.0;
  const long long total = (long long)L * (long long)L;
  for (long long idx = (long long)b*256 + t; idx < total; idx += (long long)512*256){
    #pragma clang fp contract(off)
    int i = (int)(idx >> 12), j = (int)(idx & 4095);
    double p0 = cz[i*2] * cz[j*2];
    double p1 = cz[i*2+1] * cz[j*2+1];
    double g = p0 + p1;
    double d2 = (sq[i] + sq[j]) - 2.0*g;
    d2 = d2 > 0.0 ? d2 : 0.0;
    double d = sqrt(d2) - mean;
    s += d * d;
  }
  __shared__ double r1[256];
  r1[t] = s; __syncthreads();
  for (int w = 128; w >= 1; w >>= 1){ if (t < w) r1[t] += r1[t+w]; __syncthreads(); }
  if (t == 0) sp2[b] = r1[0];
}

__global__ void k_consts(const float* __restrict__ wp, char* ws){
  const double* sp2 = (const double*)(ws + OFF_SP2);
  double* cst = (double*)(ws + OFF_CONST);
  int t = threadIdx.x; // 256
  __shared__ double r1[256];
  double a = sp2[t] + sp2[256 + t];
  r1[t] = a; __syncthreads();
  for (int w = 128; w >= 1; w >>= 1){ if (t < w) r1[t] += r1[t+w]; __syncthreads(); }
  if (t == 0){
    double N = (double)L * (double)L;
    double var = r1[0] / (N - 1.0);
    cst[0] = sqrt(var) + 1e-6;
    double a0 = (double)wp[0], a1 = (double)wp[1];
    double m = a0 > a1 ? a0 : a1;
    double e0 = exp(a0 - m), e1 = exp(a1 - m);
    cst[1] = e0 / (e0 + e1);
    cst[2] = e1 / (e0 + e1);
  }
}

// =============== K5: fused fp64 sim GEMM + per-row top-10 -> knn features ===============
// 8 rows/block, 512 blocks, 512 threads; 8 column passes of 512.
__launch_bounds__(512, 1)
__global__ void k_simtopk(char* ws){
  const double* fz = (const double*)(ws + OFF_FZ);
  const double* cz = (const double*)(ws + OFF_CZ);
  const double* sq = (const double*)(ws + OFF_SQ);
  const double* cst = (const double*)(ws + OFF_CONST);
  double* knn = (double*)(ws + OFF_KNN);
  __shared__ __align__(16) double Afz[8*384];   // 24.6 KB
  __shared__ double simt[8*513];                // 32.8 KB
  __shared__ double Acz[16], Asq[8];
  int t = threadIdx.x;
  int i0 = blockIdx.x * 8;
  for (int idx = t; idx < 8*384; idx += 512) Afz[idx] = fz[(size_t)i0*C + idx];
  if (t < 8){ Asq[t] = sq[i0 + t]; Acz[2*t] = cz[(i0+t)*2]; Acz[2*t+1] = cz[(i0+t)*2+1]; }
  double sigma = cst[0], w0 = cst[1], w1 = cst[2];
  double t10[10];
  #pragma unroll
  for (int q = 0; q < 10; q++) t10[q] = -INFINITY;
  __syncthreads();

  for (int p = 0; p < 8; p++){
    int j = p*512 + t;
    double acc[8];
    #pragma unroll
    for (int r = 0; r < 8; r++) acc[r] = 0.0;
    const double2* bj = (const double2*)(fz + (size_t)j*C);
    for (int k2 = 0; k2 < 192; k2++){
      double2 b = bj[k2];
      #pragma unroll
      for (int r = 0; r < 8; r++){
        const double2 a = *(const double2*)(&Afz[r*384 + k2*2]);
        acc[r] += a.x*b.x + a.y*b.y;
      }
    }
    {
      #pragma clang fp contract(off)
      double cj0 = cz[j*2], cj1 = cz[j*2+1], sj = sq[j];
      for (int r = 0; r < 8; r++){
        double p0 = Acz[2*r]*cj0; double p1 = Acz[2*r+1]*cj1;
        double g = p0 + p1;
        double d2 = (Asq[r] + sj) - 2.0*g;
        d2 = d2 > 0.0 ? d2 : 0.0;
        double dst = sqrt(d2);
        double e = exp(-dst / sigma);
        double u0 = w0*acc[r]; double u1 = w1*e;
        simt[r*513 + t] = u0 + u1;
      }
    }
    __syncthreads();
    if (t < 64){
      int r = t & 7, g = t >> 3;
      const double* row = &simt[r*513 + g*64];
      for (int q = 0; q < 64; q++){
        double v = row[q];
        if (v > t10[9]){
          t10[9] = v;
          #pragma unroll
          for (int u = 9; u >= 1; --u){
            if (t10[u] > t10[u-1]){ double tmp = t10[u-1]; t10[u-1] = t10[u]; t10[u] = tmp; }
          }
        }
      }
    }
    __syncthreads();
  }
  // merge 8 partial lists per row
  if (t < 64){
    int r = t & 7, g = t >> 3;
    #pragma unroll
    for (int q = 0; q < 10; q++) simt[(r*8+g)*10 + q] = t10[q];
  }
  __syncthreads();
  if (t < 8){
    double f10[10];
    #pragma unroll
    for (int q = 0; q < 10; q++) f10[q] = -INFINITY;
    for (int g = 0; g < 8; g++){
      for (int q = 0; q < 10; q++){
        double v = simt[(t*8+g)*10 + q];
        if (v > f10[9]){
          f10[9] = v;
          #pragma unroll
          for (int u = 9; u >= 1; --u){
            if (f10[u] > f10[u-1]){ double tmp = f10[u-1]; f10[u-1] = f10[u]; f10[u] = tmp; }
          }
        }
      }
    }
    double s = 0.0;
    #pragma unroll
    for (int q = 0; q < 10; q++) s += f10[q];
    s = s + 1e-6;
    #pragma unroll
    for (int q = 0; q < 10; q++) knn[(size_t)(i0 + t)*KNN + q] = f10[q] / s;
  }
}

// =============== K6: KMeans fp64 (8 blocks x 512, int64 fixed-point, spin barrier) ===============
__device__ __forceinline__ void gbar(int* bar, int target){
  __syncthreads();
  if (threadIdx.x == 0){
    __hip_atomic_fetch_add(bar, 1, __ATOMIC_ACQ_REL, SCOPE_AGENT);
    while (__hip_atomic_load(bar, __ATOMIC_ACQUIRE, SCOPE_AGENT) < target){
      __builtin_amdgcn_s_sleep(4);
    }
  }
  __syncthreads();
}

__launch_bounds__(512, 1)
__global__ void k_kmeans(char* ws){
  const double* knn = (const double*)(ws + OFF_KNN);
  int* labels = (int*)(ws + OFF_LBL);
  KCtrl* ct = (KCtrl*)(ws + OFF_CTRL);
  int t = threadIdx.x, b = blockIdx.x;
  int P = b*512 + t;
  double x[10];
  #pragma unroll
  for (int d = 0; d < 10; d++) x[d] = knn[(size_t)P*KNN + d];
  __shared__ double cen[160];
  if (t < 160) cen[t] = knn[(size_t)(273*(t/10))*KNN + (t % 10)];  // init_idx[c] = 273*c
  __syncthreads();
  int prev = -1, label = 0;
  int it = 0;
  for (; it < KM_ITERS; ++it){
    // --- assignment (exact reference formula, sequential d) ---
    double best = INFINITY; int bi = 0;
    for (int c = 0; c < 16; ++c){
      #pragma clang fp contract(off)
      double dd = 0.0;
      #pragma unroll
      for (int d = 0; d < 10; ++d){ double df = x[d] - cen[c*10 + d]; double s2 = df*df; dd = dd + s2; }
      if (dd < best){ best = dd; bi = c; }
    }
    label = bi;
    int slot = it % 3;
    // --- accumulate (order-independent int64 fixed point, quant err ~2^-53) ---
    #pragma unroll
    for (int d = 0; d < 10; d++){
      long long q = llrint(x[d] * FXS);
      __hip_atomic_fetch_add(&ct->sums[slot][bi*10 + d], (u64)q, __ATOMIC_RELAXED, SCOPE_AGENT);
    }
    __hip_atomic_fetch_add(&ct->cnt[slot][bi], 1, __ATOMIC_RELAXED, SCOPE_AGENT);
    u64 mb = __ballot(label != prev);
    if (((t & 63) == 0) && mb)
      __hip_atomic_fetch_add(&ct->chg[slot], (int)__popcll(mb), __ATOMIC_RELAXED, SCOPE_AGENT);
    prev = label;
    // --- one barrier per iter ---
    gbar(&ct->bar, 8*(it+1));
    int chg = __hip_atomic_load(&ct->chg[slot], __ATOMIC_RELAXED, SCOPE_AGENT);
    int zslot = (it + 2) % 3;
    if (t < 160){
      u64 sv = __hip_atomic_load(&ct->sums[slot][t], __ATOMIC_RELAXED, SCOPE_AGENT);
      int cc = __hip_atomic_load(&ct->cnt[slot][t/10], __ATOMIC_RELAXED, SCOPE_AGENT);
      double s = (double)(long long)sv * (1.0 / FXS);
      double cd = (double)cc;
      double nc = s / (cd > 1.0 ? cd : 1.0);
      if (cc > 0) cen[t] = nc;  // else keep old center (reference jnp.where)
      __hip_atomic_store(&ct->sums[zslot][t], (u64)0, __ATOMIC_RELAXED, SCOPE_AGENT);
    }
    if (t < 16) __hip_atomic_store(&ct->cnt[zslot][t], 0, __ATOMIC_RELAXED, SCOPE_AGENT);
    if (t == 0) __hip_atomic_store(&ct->chg[zslot], 0, __ATOMIC_RELAXED, SCOPE_AGENT);
    __syncthreads();
    if (chg == 0) break;  // exact fixed point: remaining iters are bitwise no-ops
  }
  if (it == KM_ITERS){
    // final assignment with final centers
    double best = INFINITY; int bi = 0;
    for (int c = 0; c < 16; ++c){
      #pragma clang fp contract(off)
      double dd = 0.0;
      #pragma unroll
      for (int d = 0; d < 10; ++d){ double df = x[d] - cen[c*10 + d]; double s2 = df*df; dd = dd + s2; }
      if (dd < best){ best = dd; bi = c; }
    }
    label = bi;
  }
  labels[P] = label;
}

// =============== K7: stable counting sort -> member order + offsets ===============
__global__ void k_order(char* ws){ // 1 block x 64 (single wave)
  const int* labels = (const int*)(ws + OFF_LBL);
  int* order = (int*)(ws + OFF_ORD);
  int* offs  = (int*)(ws + OFF_OFFS);
  int t = threadIdx.x;
  __shared__ int cnt[16];
  volatile __shared__ int base[17];
  int my = 0;
  for (int ch = 0; ch < 64; ch++){
    int l = labels[ch*64 + t];
    for (int c = 0; c < 16; c++){
      u64 m = __ballot(l == c);
      if (t == c) my += (int)__popcll(m);
    }
  }
  if (t < 16) cnt[t] = my;
  __syncthreads();
  if (t == 0){
    int a = 0;
    for (int c = 0; c < 16; c++){ base[c] = a; a += cnt[c]; }
    base[16] = a;
    for (int c = 0; c < 17; c++) offs[c] = base[c];
  }
  __syncthreads();
  u64 lower = (t == 0) ? 0ull : ((1ull << t) - 1ull);
  for (int ch = 0; ch < 64; ch++){
    int i = ch*64 + t;
    int l = labels[i];
    for (int c = 0; c < 16; c++){
      u64 m = __ballot(l == c);
      int bc = base[c];                       // read before update (wave in-order)
      if (l == c){ int pos = bc + (int)__popcll(m & lower); order[pos] = i; }
      if (t == c) base[c] = bc + (int)__popcll(m);
    }
  }
}

// =============== K8: qkv = x @ w_in^T + b_in (fp32) ===============
__launch_bounds__(384, 1)
__global__ void k_qkv(const float* __restrict__ x, const float* __restrict__ w_in,
                      const float* __restrict__ b_in, char* ws){
  float* qkv = (float*)(ws + OFF_QKV);
  int b = blockIdx.x, t = threadIdx.x;
  int r0 = b*8;
  __shared__ __align__(16) float xs[8*384];
  for (int idx = t; idx < 8*384; idx += 384) xs[idx] = x[r0*C + idx];
  __syncthreads();
  for (int og = 0; og < 3; og++){
    int o = og*384 + t;
    const float* wr = w_in + (size_t)o*C;
    float acc[8];
    #pragma unroll
    for (int r = 0; r < 8; r++) acc[r] = 0.f;
    for (int k = 0; k < 384; k += 4){
      float4 wv = *(const float4*)(wr + k);
      #pragma unroll
      for (int r = 0; r < 8; r++){
        const float4 xv = *(const float4*)(&xs[r*384 + k]);
        acc[r] += xv.x*wv.x + xv.y*wv.y + xv.z*wv.z + xv.w*wv.w;
      }
    }
    float bias = b_in[o];
    #pragma unroll
    for (int r = 0; r < 8; r++) qkv[(size_t)(r0+r)*C3 + o] = acc[r] + bias;
  }
}

// =============== K9: per-cluster masked attention (online softmax, wave per query) ===============
__launch_bounds__(256, 1)
__global__ void k_cattn(char* ws){
  const float* qkv = (const float*)(ws + OFF_QKV);
  const int* order = (const int*)(ws + OFF_ORD);
  const int* offs  = (const int*)(ws + OFF_OFFS);
  float* attn = (float*)(ws + OFF_ATTN);
  int c = blockIdx.x;
  int w = threadIdx.x >> 6, lane = threadIdx.x & 63;
  int off = offs[c];
  int n = offs[c+1] - off;
  __shared__ __align__(16) float qs[4][384];
  for (int qi = blockIdx.y*4 + w; qi < n; qi += 1024){
    int r = order[off + qi];
    for (int idx = lane; idx < 384; idx += 64) qs[w][idx] = qkv[(size_t)r*C3 + idx];
    __threadfence_block();
    for (int h = 0; h < 8; h++){
      float m = -INFINITY, lsum = 0.f, acc = 0.f;
      const float* qh = &qs[w][h*HD];
      for (int base = 0; base < n; base += 64){
        int j = base + lane;
        int mj = 0; float s = -INFINITY;
        if (j < n){
          mj = order[off + j];
          const float4* kr = (const float4*)(qkv + (size_t)mj*C3 + 384 + h*HD);
          float dot = 0.f;
          #pragma unroll
          for (int q4 = 0; q4 < 12; q4++){
            float4 kv = kr[q4];
            const float4 qv = *(const float4*)(qh + q4*4);
            dot += qv.x*kv.x + qv.y*kv.y + qv.z*kv.z + qv.w*kv.w;
          }
          s = dot / 6.92820323027551f;  // sqrt(48)
        }
        float cm = s;
        #pragma unroll
        for (int d = 32; d >= 1; d >>= 1) cm = fmaxf(cm, __shfl_xor(cm, d));
        float nm = fmaxf(m, cm);
        float alpha = expf(m - nm);
        float p = (j < n) ? expf(s - nm) : 0.f;
        float cs = p;
        #pragma unroll
        for (int d = 32; d >= 1; d >>= 1) cs += __shfl_xor(cs, d);
        lsum = lsum*alpha + cs;
        acc *= alpha;
        int lim = (n - base < 64) ? (n - base) : 64;
        for (int jj = 0; jj < lim; jj++){
          float pv = __shfl(p, jj);
          int mv = __shfl(mj, jj);
          if (lane < 48) acc += pv * qkv[(size_t)mv*C3 + 768 + h*HD + lane];
        }
        m = nm;
      }
      if (lane < 48) attn[(size_t)r*C + h*HD + lane] = acc / lsum;
    }
  }
}

// =============== K10: out-proj + residual + LayerNorm -> h ===============
__launch_bounds__(384, 1)
__global__ void k_outln(const float* __restrict__ x, const float* __restrict__ w_out,
                        const float* __restrict__ b_out, const float* __restrict__ g,
                        const float* __restrict__ bb, char* ws){
  const float* attn = (const float*)(ws + OFF_ATTN);
  float* h = (float*)(ws + OFF_H);
  int b = blockIdx.x, t = threadIdx.x;
  int r0 = b*8;
  __shared__ __align__(16) float as[8*384];
  __shared__ float ov[8*384];
  __shared__ float red[8*48];
  __shared__ float stats[16];
  for (int idx = t; idx < 8*384; idx += 384) as[idx] = attn[(size_t)r0*C + idx];
  __syncthreads();
  const float* wr = w_out + (size_t)t*C;
  float acc[8];
  #pragma unroll
  for (int r = 0; r < 8; r++) acc[r] = 0.f;
  for (int k = 0; k < 384; k += 4){
    float4 wv = *(const float4*)(wr + k);
    #pragma unroll
    for (int r = 0; r < 8; r++){
      const float4 av = *(const float4*)(&as[r*384 + k]);
      acc[r] += av.x*wv.x + av.y*wv.y + av.z*wv.z + av.w*wv.w;
    }
  }
  float bias = b_out[t];
  #pragma unroll
  for (int r = 0; r < 8; r++){
    float v = acc[r] + bias + x[(size_t)(r0+r)*C + t];
    ov[r*384 + t] = v;
  }
  __syncthreads();
  int rr = t & 7, ii = t >> 3;  // 8 rows x 48 partials
  float ps = 0.f;
  for (int j = ii; j < 384; j += 48) ps += ov[rr*384 + j];
  red[rr*48 + ii] = ps; __syncthreads();
  if (t < 8){ float s = 0.f; for (int q = 0; q < 48; q++) s += red[t*48 + q]; stats[t] = s / 384.f; }
  __syncthreads();
  float mu = stats[rr];
  float pv = 0.f;
  for (int j = ii; j < 384; j += 48){ float d = ov[rr*384 + j] - mu; pv += d*d; }
  red[rr*48 + ii] = pv; __syncthreads();
  if (t < 8){ float s = 0.f; for (int q = 0; q < 48; q++) s += red[t*48 + q]; stats[8 + t] = s / 384.f; }
  __syncthreads();
  #pragma unroll
  for (int r = 0; r < 8; r++){
    float mu2 = stats[r], var = stats[8 + r];
    float v = ov[r*384 + t];
    h[(size_t)(r0+r)*C + t] = (v - mu2) / sqrtf(var + 1e-5f) * g[t] + bb[t];
  }
}

// =============== K11: cluster means of h -> reps ===============
__global__ void k_reps(char* ws){ // 16 x 384
  const float* h = (const float*)(ws + OFF_H);
  const int* order = (const int*)(ws + OFF_ORD);
  const int* offs  = (const int*)(ws + OFF_OFFS);
  float* reps = (float*)(ws + OFF_REPS);
  int c = blockIdx.x, t = threadIdx.x;
  int o0 = offs[c], o1 = offs[c+1];
  float acc = 0.f;
  for (int idx = o0; idx < o1; idx++){ int r = order[idx]; acc += h[(size_t)r*C + t]; }
  float cntf = (float)(o1 - o0);
  reps[c*C + t] = acc / fmaxf(cntf, 1.f);
}

// =============== K12: gqkv = reps @ gw_in^T + gb_in ===============
__global__ void k_gqkv(const float* __restrict__ gw_in, const float* __restrict__ gb_in, char* ws){
  const float* reps = (const float*)(ws + OFF_REPS);
  float* gqkv = (float*)(ws + OFF_GQKV);
  int c = blockIdx.x / 3, og = blockIdx.x % 3;
  int t = threadIdx.x;
  __shared__ __align__(16) float rs[384];
  rs[t] = reps[c*C + t]; __syncthreads();
  int o = og*384 + t;
  const float* wr = gw_in + (size_t)o*C;
  float acc = 0.f;
  for (int k = 0; k < 384; k += 4){
    float4 wv = *(const float4*)(wr + k);
    const float4 rv = *(const float4*)(&rs[k]);
    acc += rv.x*wv.x + rv.y*wv.y + rv.z*wv.z + rv.w*wv.w;
  }
  gqkv[c*C3 + o] = acc + gb_in[o];
}

// =============== K13: global attention on reps (16 keys, no mask) ===============
__global__ void k_gattn(char* ws){ // 16 x 64
  const float* gq = (const float*)(ws + OFF_GQKV);
  float* ga = (float*)(ws + OFF_GATT);
  int c = blockIdx.x, lane = threadIdx.x;
  __shared__ float sc[16], pr[16];
  for (int h = 0; h < 8; h++){
    if (lane < 16){
      float dot = 0.f;
      const float* qv = gq + c*C3 + h*HD;
      const float* kv = gq + lane*C3 + 384 + h*HD;
      for (int d = 0; d < 48; d++) dot += qv[d]*kv[d];
      sc[lane] = dot / 6.92820323027551f;
    }
    __threadfence_block();
    if (lane == 0){
      float mx = -INFINITY;
      for (int j = 0; j < 16; j++) mx = fmaxf(mx, sc[j]);
      float sum = 0.f;
      for (int j = 0; j < 16; j++){ float e = expf(sc[j] - mx); pr[j] = e; sum += e; }
      for (int j = 0; j < 16; j++) pr[j] /= sum;
    }
    __threadfence_block();
    if (lane < 48){
      float acc = 0.f;
      for (int j = 0; j < 16; j++) acc += pr[j] * gq[j*C3 + 768 + h*HD + lane];
      ga[c*C + h*HD + lane] = acc;
    }
    __threadfence_block();
  }
}

// =============== K14: global out-proj + residual + LN -> greps ===============
__global__ void k_goutln(const float* __restrict__ gw_out, const float* __restrict__ gb_out,
                         const float* __restrict__ gg, const float* __restrict__ gb2, char* ws){
  const float* ga = (const float*)(ws + OFF_GATT);
  const float* reps = (const float*)(ws + OFF_REPS);
  float* grep = (float*)(ws + OFF_GREP);
  int c = blockIdx.x, t = threadIdx.x; // 384
  __shared__ __align__(16) float as[384];
  __shared__ float ov[384];
  __shared__ float red[64];
  __shared__ float st[2];
  as[t] = ga[c*C + t]; __syncthreads();
  const float* wr = gw_out + (size_t)t*C;
  float acc = 0.f;
  for (int k = 0; k < 384; k += 4){
    float4 wv = *(const float4*)(wr + k);
    const float4 av = *(const float4*)(&as[k]);
    acc += av.x*wv.x + av.y*wv.y + av.z*wv.z + av.w*wv.w;
  }
  float v = acc + gb_out[t] + reps[c*C + t];
  ov[t] = v; __syncthreads();
  if (t < 64){ float s = 0.f; for (int j = t; j < 384; j += 64) s += ov[j]; red[t] = s; }
  __syncthreads();
  if (t == 0){ float s = 0.f; for (int q = 0; q < 64; q++) s += red[q]; st[0] = s / 384.f; }
  __syncthreads();
  float mu = st[0];
  if (t < 64){ float s = 0.f; for (int j = t; j < 384; j += 64){ float d = ov[j]-mu; s += d*d; } red[t] = s; }
  __syncthreads();
  if (t == 0){ float s = 0.f; for (int q = 0; q < 64; q++) s += red[q]; st[1] = s / 384.f; }
  __syncthreads();
  grep[c*C + t] = (v - mu) / sqrtf(st[1] + 1e-5f) * gg[t] + gb2[t];
}

// =============== K15/K16: reps mean + final add ===============
__global__ void k_repmean(char* ws){ // 1 x 384
  const float* grep = (const float*)(ws + OFF_GREP);
  float* rm = (float*)(ws + OFF_RMEAN);
  int t = threadIdx.x;
  float s = 0.f;
  for (int c = 0; c < 16; c++) s += grep[c*C + t];
  rm[t] = s / 16.f;
}

__global__ void k_final(char* ws, float* __restrict__ out){ // 1536 x 256 (float4)
  const float4* h = (const float4*)(ws + OFF_H);
  const float4* rm = (const float4*)(ws + OFF_RMEAN);
  int idx = blockIdx.x*256 + threadIdx.x;
  float4 hv = h[idx];
  float4 rv = rm[idx % 96];
  ((float4*)out)[idx] = make_float4(hv.x + rv.x, hv.y + rv.y, hv.z + rv.z, hv.w + rv.w);
}

// ==================== launcher ====================
extern "C" void kernel_launch(void* const* d_in, const int* in_sizes, int n_in,
                              void* d_out, int out_size, void* d_ws, size_t ws_size,
                              hipStream_t stream){
  (void)in_sizes; (void)n_in; (void)out_size; (void)ws_size;
  const float* x      = (const float*)d_in[0];
  const float* coords = (const float*)d_in[1];
  const float* wp     = (const float*)d_in[2];
  const float* lw_in  = (const float*)d_in[3];
  const float* lb_in  = (const float*)d_in[4];
  const float* lw_out = (const float*)d_in[5];
  const float* lb_out = (const float*)d_in[6];
  const float* lg     = (const float*)d_in[7];
  const float* lb     = (const float*)d_in[8];
  const float* gw_in  = (const float*)d_in[9];
  const float* gb_in  = (const float*)d_in[10];
  const float* gw_out = (const float*)d_in[11];
  const float* gb_out = (const float*)d_in[12];
  const float* gg     = (const float*)d_in[13];
  const float* gb     = (const float*)d_in[14];
  char* ws = (char*)d_ws;

  hipMemsetAsync(ws + OFF_CTRL, 0, AL(CTRL_BYTES), stream);
  hipLaunchKernelGGL(k_colstats,  dim3(25),       dim3(256), 0, stream, x, coords, ws);
  hipLaunchKernelGGL(k_normalize, dim3(4096),     dim3(128), 0, stream, x, coords, ws);
  hipLaunchKernelGGL(k_sigsum,    dim3(512),      dim3(256), 0, stream, ws);
  hipLaunchKernelGGL(k_sigmean,   dim3(1),        dim3(256), 0, stream, ws);
  hipLaunchKernelGGL(k_sigvar,    dim3(512),      dim3(256), 0, stream, ws);
  hipLaunchKernelGGL(k_consts,    dim3(1),        dim3(256), 0, stream, wp, ws);
  hipLaunchKernelGGL(k_simtopk,   dim3(512),      dim3(512), 0, stream, ws);
  hipLaunchKernelGGL(k_kmeans,    dim3(8),        dim3(512), 0, stream, ws);
  hipLaunchKernelGGL(k_order,     dim3(1),        dim3(64),  0, stream, ws);
  hipLaunchKernelGGL(k_qkv,       dim3(512),      dim3(384), 0, stream, x, lw_in, lb_in, ws);
  hipLaunchKernelGGL(k_cattn,     dim3(16, 256),  dim3(256), 0, stream, ws);
  hipLaunchKernelGGL(k_outln,     dim3(512),      dim3(384), 0, stream, x, lw_out, lb_out, lg, lb, ws);
  hipLaunchKernelGGL(k_reps,      dim3(16),       dim3(384), 0, stream, ws);
  hipLaunchKernelGGL(k_gqkv,      dim3(48),       dim3(384), 0, stream, gw_in, gb_in, ws);
  hipLaunchKernelGGL(k_gattn,     dim3(16),       dim3(64),  0, stream, ws);
  hipLaunchKernelGGL(k_goutln,    dim3(16),       dim3(384), 0, stream, gw_out, gb_out, gg, gb, ws);
  hipLaunchKernelGGL(k_repmean,   dim3(1),        dim3(384), 0, stream, ws);
  hipLaunchKernelGGL(k_final,     dim3(1536),     dim3(256), 0, stream, ws, (float*)d_out);
}

// Round 3
// 3884.864 us; speedup vs baseline: 1.5448x; 1.5448x over previous
//
#include <hip/hip_runtime.h>
#include <math.h>
#include <stdint.h>

typedef unsigned long long u64;

// ---------------- problem constants ----------------
constexpr int L  = 4096;
constexpr int C  = 384;
constexpr int C3 = 1152;
constexpr int HD = 48;
constexpr int NCL = 16;
constexpr int KNN = 10;
constexpr int KM_ITERS = 50;

// ---------------- workspace layout (bytes) ----------------
// fz (double[L][C], 12.58MB) is dead before qkv (float[L][C3], 18.87MB) is
// written -> they share one region.
constexpr size_t AL(size_t x){ return (x + 255) & ~size_t(255); }
constexpr size_t OFF_AB    = 0;                                       // union fz/qkv
constexpr size_t OFF_FZ    = OFF_AB;                                  // double [L][C]
constexpr size_t OFF_QKV   = OFF_AB;                                  // float [L][C3]
constexpr size_t OFF_ATTN  = AL(OFF_AB    + sizeof(float)*L*C3);      // float [L][C]
constexpr size_t OFF_H     = AL(OFF_ATTN  + sizeof(float)*L*C);       // float [L][C]
constexpr size_t OFF_CZ    = AL(OFF_H     + sizeof(float)*L*C);       // double [L][2]
constexpr size_t OFF_SQ    = AL(OFF_CZ    + sizeof(double)*L*2);      // double [L]
constexpr size_t OFF_CM    = AL(OFF_SQ    + sizeof(double)*L);        // double [C]
constexpr size_t OFF_CD    = AL(OFF_CM    + sizeof(double)*C);        // double [C]
constexpr size_t OFF_CCM   = AL(OFF_CD    + sizeof(double)*C);        // double [2]
constexpr size_t OFF_CCD   = AL(OFF_CCM   + sizeof(double)*2);        // double [2]
constexpr size_t OFF_SP    = AL(OFF_CCD   + sizeof(double)*2);        // double [512]
constexpr size_t OFF_SP2   = AL(OFF_SP    + sizeof(double)*512);      // double [512]
constexpr size_t OFF_CONST = AL(OFF_SP2   + sizeof(double)*512);      // double [8]: sigma,w0,w1,meandist
constexpr size_t OFF_KNN   = AL(OFF_CONST + sizeof(double)*8);        // double [L][KNN]
constexpr size_t OFF_LBL   = AL(OFF_KNN   + sizeof(double)*L*KNN);    // int [L]
constexpr size_t OFF_ORD   = AL(OFF_LBL   + sizeof(int)*L);           // int [L]
constexpr size_t OFF_OFFS  = AL(OFF_ORD   + sizeof(int)*L);           // int [17]
constexpr size_t OFF_REPS  = AL(OFF_OFFS  + sizeof(int)*32);          // float [16][C]
constexpr size_t OFF_GQKV  = AL(OFF_REPS  + sizeof(float)*NCL*C);     // float [16][C3]
constexpr size_t OFF_GATT  = AL(OFF_GQKV  + sizeof(float)*NCL*C3);    // float [16][C]
constexpr size_t OFF_GREP  = AL(OFF_GATT  + sizeof(float)*NCL*C);     // float [16][C]
constexpr size_t OFF_RMEAN = AL(OFF_GREP  + sizeof(float)*NCL*C);     // float [C]
constexpr size_t OFF_CTRL  = AL(OFF_RMEAN + sizeof(float)*C);         // kmeans control (memset 0)

struct KCtrl {
  u64 sums[3][160];   // int64 fixed-point (2^52) center sums, 3-slot rotation
  int cnt[3][16];
  int chg[3];
  int bar;
};
constexpr size_t CTRL_BYTES = sizeof(KCtrl);
constexpr double FXS = 4503599627370496.0;   // 2^52

#define SCOPE_AGENT __HIP_MEMORY_SCOPE_AGENT

// =============== K1: per-column mean / std(ddof=1), fp64 ===============
__global__ void k_colstats(const float* __restrict__ x, const float* __restrict__ coords, char* ws){
  double* colm = (double*)(ws + OFF_CM);
  double* cold = (double*)(ws + OFF_CD);
  double* ccm  = (double*)(ws + OFF_CCM);
  double* ccd  = (double*)(ws + OFF_CCD);
  int b = blockIdx.x, t = threadIdx.x;
  __shared__ double red[256];
  __shared__ double muS[16];
  if (b < 24) {
    int co = t & 15, rg = t >> 4;
    int col = b*16 + co;
    double s = 0.0;
    for (int r = rg; r < L; r += 16) s += (double)x[r*C + col];
    red[t] = s; __syncthreads();
    for (int w = 8; w >= 1; w >>= 1){ if (rg < w) red[t] += red[t + w*16]; __syncthreads(); }
    if (rg == 0) muS[co] = red[co] / 4096.0;
    __syncthreads();
    double mu = muS[co];
    double ss = 0.0;
    for (int r = rg; r < L; r += 16){ double d = (double)x[r*C + col] - mu; ss += d * d; }
    red[t] = ss; __syncthreads();
    for (int w = 8; w >= 1; w >>= 1){ if (rg < w) red[t] += red[t + w*16]; __syncthreads(); }
    if (rg == 0){ colm[col] = mu; cold[col] = sqrt(red[co] / 4095.0) + 1e-6; }
  } else {
    int co = t & 1, rg = t >> 1;   // 128 row-groups x 2 cols
    double s = 0.0;
    for (int r = rg; r < L; r += 128) s += (double)coords[r*2 + co];
    red[t] = s; __syncthreads();
    for (int w = 64; w >= 1; w >>= 1){ if (rg < w) red[t] += red[t + w*2]; __syncthreads(); }
    if (rg == 0) muS[co] = red[co] / 4096.0;
    __syncthreads();
    double mu = muS[co];
    double ss = 0.0;
    for (int r = rg; r < L; r += 128){ double d = (double)coords[r*2 + co] - mu; ss += d * d; }
    red[t] = ss; __syncthreads();
    for (int w = 64; w >= 1; w >>= 1){ if (rg < w) red[t] += red[t + w*2]; __syncthreads(); }
    if (rg == 0){ ccm[co] = mu; ccd[co] = sqrt(red[co] / 4095.0) + 1e-6; }
  }
}

// =============== K2: fz (z-score + row L2-normalize), cz, sq — fp64 ===============
__global__ void k_normalize(const float* __restrict__ x, const float* __restrict__ coords, char* ws){
  double* fz = (double*)(ws + OFF_FZ);
  double* cz = (double*)(ws + OFF_CZ);
  double* sq = (double*)(ws + OFF_SQ);
  const double* colm = (const double*)(ws + OFF_CM);
  const double* cold = (const double*)(ws + OFF_CD);
  const double* ccm  = (const double*)(ws + OFF_CCM);
  const double* ccd  = (const double*)(ws + OFF_CCD);
  int i = blockIdx.x, t = threadIdx.x; // 128 threads
  double z[3];
  #pragma unroll
  for (int q = 0; q < 3; q++){ int c = t + q*128; z[q] = ((double)x[i*C + c] - colm[c]) / cold[c]; }
  __shared__ double red[128];
  __shared__ double nrmS;
  double s = z[0]*z[0] + z[1]*z[1] + z[2]*z[2];
  red[t] = s; __syncthreads();
  for (int w = 64; w >= 1; w >>= 1){ if (t < w) red[t] += red[t + w]; __syncthreads(); }
  if (t == 0){ double n = sqrt(red[0]); nrmS = n > 1e-12 ? n : 1e-12; }
  __syncthreads();
  double n = nrmS;
  #pragma unroll
  for (int q = 0; q < 3; q++){ int c = t + q*128; fz[(size_t)i*C + c] = z[q] / n; }
  if (t == 0){
    #pragma clang fp contract(off)
    double c0 = ((double)coords[i*2 + 0] - ccm[0]) / ccd[0];
    double c1 = ((double)coords[i*2 + 1] - ccm[1]) / ccd[1];
    cz[i*2 + 0] = c0; cz[i*2 + 1] = c1;
    double p0 = c0*c0; double p1 = c1*c1;
    sq[i] = p0 + p1;
  }
}

// =============== K3a/K3b/K3c/K4: sigma = std(dist, ddof=1), two-pass fp64 ===============
__global__ void k_sigsum(char* ws){
  const double* cz = (const double*)(ws + OFF_CZ);
  const double* sq = (const double*)(ws + OFF_SQ);
  double* sp = (double*)(ws + OFF_SP);
  int b = blockIdx.x, t = threadIdx.x; // 512 x 256
  double s = 0.0;
  const long long total = (long long)L * (long long)L;
  for (long long idx = (long long)b*256 + t; idx < total; idx += (long long)512*256){
    #pragma clang fp contract(off)
    int i = (int)(idx >> 12), j = (int)(idx & 4095);
    double p0 = cz[i*2] * cz[j*2];
    double p1 = cz[i*2+1] * cz[j*2+1];
    double g = p0 + p1;
    double d2 = (sq[i] + sq[j]) - 2.0*g;
    d2 = d2 > 0.0 ? d2 : 0.0;
    s += sqrt(d2);
  }
  __shared__ double r1[256];
  r1[t] = s; __syncthreads();
  for (int w = 128; w >= 1; w >>= 1){ if (t < w) r1[t] += r1[t+w]; __syncthreads(); }
  if (t == 0) sp[b] = r1[0];
}

__global__ void k_sigmean(char* ws){
  const double* sp = (const double*)(ws + OFF_SP);
  double* cst = (double*)(ws + OFF_CONST);
  int t = threadIdx.x; // 256
  __shared__ double r1[256];
  double a = sp[t] + sp[256 + t];
  r1[t] = a; __syncthreads();
  for (int w = 128; w >= 1; w >>= 1){ if (t < w) r1[t] += r1[t+w]; __syncthreads(); }
  if (t == 0) cst[3] = r1[0] / ((double)L * (double)L);
}

__global__ void k_sigvar(char* ws){
  const double* cz = (const double*)(ws + OFF_CZ);
  const double* sq = (const double*)(ws + OFF_SQ);
  const double* cst = (const double*)(ws + OFF_CONST);
  double* sp2 = (double*)(ws + OFF_SP2);
  int b = blockIdx.x, t = threadIdx.x; // 512 x 256
  double mean = cst[3];
  double s = 0.0;
  const long long total = (long long)L * (long long)L;
  for (long long idx = (long long)b*256 + t; idx < total; idx += (long long)512*256){
    #pragma clang fp contract(off)
    int i = (int)(idx >> 12), j = (int)(idx & 4095);
    double p0 = cz[i*2] * cz[j*2];
    double p1 = cz[i*2+1] * cz[j*2+1];
    double g = p0 + p1;
    double d2 = (sq[i] + sq[j]) - 2.0*g;
    d2 = d2 > 0.0 ? d2 : 0.0;
    double d = sqrt(d2) - mean;
    s += d * d;
  }
  __shared__ double r1[256];
  r1[t] = s; __syncthreads();
  for (int w = 128; w >= 1; w >>= 1){ if (t < w) r1[t] += r1[t+w]; __syncthreads(); }
  if (t == 0) sp2[b] = r1[0];
}

__global__ void k_consts(const float* __restrict__ wp, char* ws){
  const double* sp2 = (const double*)(ws + OFF_SP2);
  double* cst = (double*)(ws + OFF_CONST);
  int t = threadIdx.x; // 256
  __shared__ double r1[256];
  double a = sp2[t] + sp2[256 + t];
  r1[t] = a; __syncthreads();
  for (int w = 128; w >= 1; w >>= 1){ if (t < w) r1[t] += r1[t+w]; __syncthreads(); }
  if (t == 0){
    double N = (double)L * (double)L;
    double var = r1[0] / (N - 1.0);
    cst[0] = sqrt(var) + 1e-6;
    double a0 = (double)wp[0], a1 = (double)wp[1];
    double m = a0 > a1 ? a0 : a1;
    double e0 = exp(a0 - m), e1 = exp(a1 - m);
    cst[1] = e0 / (e0 + e1);
    cst[2] = e1 / (e0 + e1);
  }
}

// =============== K5: fused fp64 sim GEMM + per-row top-10 -> knn features ===============
// 8 rows/block, 512 blocks, 512 threads; 8 column passes of 512.
__launch_bounds__(512, 1)
__global__ void k_simtopk(char* ws){
  const double* fz = (const double*)(ws + OFF_FZ);
  const double* cz = (const double*)(ws + OFF_CZ);
  const double* sq = (const double*)(ws + OFF_SQ);
  const double* cst = (const double*)(ws + OFF_CONST);
  double* knn = (double*)(ws + OFF_KNN);
  __shared__ __align__(16) double Afz[8*384];   // 24.6 KB
  __shared__ double simt[8*513];                // 32.8 KB
  __shared__ double Acz[16], Asq[8];
  int t = threadIdx.x;
  int i0 = blockIdx.x * 8;
  for (int idx = t; idx < 8*384; idx += 512) Afz[idx] = fz[(size_t)i0*C + idx];
  if (t < 8){ Asq[t] = sq[i0 + t]; Acz[2*t] = cz[(i0+t)*2]; Acz[2*t+1] = cz[(i0+t)*2+1]; }
  double sigma = cst[0], w0 = cst[1], w1 = cst[2];
  double t10[10];
  #pragma unroll
  for (int q = 0; q < 10; q++) t10[q] = -INFINITY;
  __syncthreads();

  for (int p = 0; p < 8; p++){
    int j = p*512 + t;
    double acc[8];
    #pragma unroll
    for (int r = 0; r < 8; r++) acc[r] = 0.0;
    const double2* bj = (const double2*)(fz + (size_t)j*C);
    for (int k2 = 0; k2 < 192; k2++){
      double2 b = bj[k2];
      #pragma unroll
      for (int r = 0; r < 8; r++){
        const double2 a = *(const double2*)(&Afz[r*384 + k2*2]);
        acc[r] += a.x*b.x + a.y*b.y;
      }
    }
    {
      #pragma clang fp contract(off)
      double cj0 = cz[j*2], cj1 = cz[j*2+1], sj = sq[j];
      for (int r = 0; r < 8; r++){
        double p0 = Acz[2*r]*cj0; double p1 = Acz[2*r+1]*cj1;
        double g = p0 + p1;
        double d2 = (Asq[r] + sj) - 2.0*g;
        d2 = d2 > 0.0 ? d2 : 0.0;
        double dst = sqrt(d2);
        double e = exp(-dst / sigma);
        double u0 = w0*acc[r]; double u1 = w1*e;
        simt[r*513 + t] = u0 + u1;
      }
    }
    __syncthreads();
    if (t < 64){
      int r = t & 7, g = t >> 3;
      const double* row = &simt[r*513 + g*64];
      for (int q = 0; q < 64; q++){
        double v = row[q];
        if (v > t10[9]){
          t10[9] = v;
          #pragma unroll
          for (int u = 9; u >= 1; --u){
            if (t10[u] > t10[u-1]){ double tmp = t10[u-1]; t10[u-1] = t10[u]; t10[u] = tmp; }
          }
        }
      }
    }
    __syncthreads();
  }
  // merge 8 partial lists per row
  if (t < 64){
    int r = t & 7, g = t >> 3;
    #pragma unroll
    for (int q = 0; q < 10; q++) simt[(r*8+g)*10 + q] = t10[q];
  }
  __syncthreads();
  if (t < 8){
    double f10[10];
    #pragma unroll
    for (int q = 0; q < 10; q++) f10[q] = -INFINITY;
    for (int g = 0; g < 8; g++){
      for (int q = 0; q < 10; q++){
        double v = simt[(t*8+g)*10 + q];
        if (v > f10[9]){
          f10[9] = v;
          #pragma unroll
          for (int u = 9; u >= 1; --u){
            if (f10[u] > f10[u-1]){ double tmp = f10[u-1]; f10[u-1] = f10[u]; f10[u] = tmp; }
          }
        }
      }
    }
    double s = 0.0;
    #pragma unroll
    for (int q = 0; q < 10; q++) s += f10[q];
    s = s + 1e-6;
    #pragma unroll
    for (int q = 0; q < 10; q++) knn[(size_t)(i0 + t)*KNN + q] = f10[q] / s;
  }
}

// =============== K6: KMeans fp64 — hierarchical reduction ===============
// 8 blocks x 512. Per-iter: LDS int64 fixed-point partials (order-independent),
// then 160 global atomics per block (was 5120) -> barrier -> center update.
// Integer sums are associative: center bits identical to the flat-atomic version.
__device__ __forceinline__ void gbar(int* bar, int target){
  __syncthreads();
  if (threadIdx.x == 0){
    __hip_atomic_fetch_add(bar, 1, __ATOMIC_ACQ_REL, SCOPE_AGENT);
    while (__hip_atomic_load(bar, __ATOMIC_ACQUIRE, SCOPE_AGENT) < target){
      __builtin_amdgcn_s_sleep(1);
    }
  }
  __syncthreads();
}

__launch_bounds__(512, 1)
__global__ void k_kmeans(char* ws){
  const double* knn = (const double*)(ws + OFF_KNN);
  int* labels = (int*)(ws + OFF_LBL);
  KCtrl* ct = (KCtrl*)(ws + OFF_CTRL);
  int t = threadIdx.x, b = blockIdx.x;
  int P = b*512 + t;
  double x[10];
  #pragma unroll
  for (int d = 0; d < 10; d++) x[d] = knn[(size_t)P*KNN + d];
  __shared__ double cen[160];
  __shared__ u64 lsum[160];
  __shared__ int lcnt[16];
  __shared__ int lchg;
  if (t < 160) cen[t] = knn[(size_t)(273*(t/10))*KNN + (t % 10)];  // init_idx[c] = 273*c
  __syncthreads();
  int prev = -1, label = 0;
  int it = 0;
  for (; it < KM_ITERS; ++it){
    // --- zero LDS partials ---
    if (t < 160) lsum[t] = 0;
    if (t < 16) lcnt[t] = 0;
    if (t == 0) lchg = 0;
    __syncthreads();
    // --- assignment (exact reference formula, sequential d) ---
    double best = INFINITY; int bi = 0;
    for (int c = 0; c < 16; ++c){
      #pragma clang fp contract(off)
      double dd = 0.0;
      #pragma unroll
      for (int d = 0; d < 10; ++d){ double df = x[d] - cen[c*10 + d]; double s2 = df*df; dd = dd + s2; }
      if (dd < best){ best = dd; bi = c; }
    }
    label = bi;
    // --- block-local accumulate (LDS int64 fixed point, order-independent) ---
    #pragma unroll
    for (int d = 0; d < 10; d++){
      long long q = llrint(x[d] * FXS);
      atomicAdd(&lsum[bi*10 + d], (u64)q);
    }
    atomicAdd(&lcnt[bi], 1);
    u64 mb = __ballot(label != prev);
    if (((t & 63) == 0) && mb) atomicAdd(&lchg, (int)__popcll(mb));
    prev = label;
    __syncthreads();
    // --- one global atomic per slot per block ---
    int slot = it % 3;
    if (t < 160){
      u64 pv = lsum[t];
      if (pv) __hip_atomic_fetch_add(&ct->sums[slot][t], pv, __ATOMIC_RELAXED, SCOPE_AGENT);
    }
    if (t < 16){
      int pc = lcnt[t];
      if (pc) __hip_atomic_fetch_add(&ct->cnt[slot][t], pc, __ATOMIC_RELAXED, SCOPE_AGENT);
    }
    if (t == 0 && lchg) __hip_atomic_fetch_add(&ct->chg[slot], lchg, __ATOMIC_RELAXED, SCOPE_AGENT);
    // --- one barrier per iter (ACQ_REL add drains prior vmem ops) ---
    gbar(&ct->bar, 8*(it+1));
    int chg = __hip_atomic_load(&ct->chg[slot], __ATOMIC_RELAXED, SCOPE_AGENT);
    int zslot = (it + 2) % 3;
    if (t < 160){
      u64 sv = __hip_atomic_load(&ct->sums[slot][t], __ATOMIC_RELAXED, SCOPE_AGENT);
      int cc = __hip_atomic_load(&ct->cnt[slot][t/10], __ATOMIC_RELAXED, SCOPE_AGENT);
      double s = (double)(long long)sv * (1.0 / FXS);
      double cd = (double)cc;
      double nc = s / (cd > 1.0 ? cd : 1.0);
      if (cc > 0) cen[t] = nc;  // else keep old center (reference jnp.where)
      __hip_atomic_store(&ct->sums[zslot][t], (u64)0, __ATOMIC_RELAXED, SCOPE_AGENT);
    }
    if (t < 16) __hip_atomic_store(&ct->cnt[zslot][t], 0, __ATOMIC_RELAXED, SCOPE_AGENT);
    if (t == 0) __hip_atomic_store(&ct->chg[zslot], 0, __ATOMIC_RELAXED, SCOPE_AGENT);
    __syncthreads();
    if (chg == 0) break;  // exact fixed point: remaining iters are bitwise no-ops
  }
  if (it == KM_ITERS){
    // final assignment with final centers
    double best = INFINITY; int bi = 0;
    for (int c = 0; c < 16; ++c){
      #pragma clang fp contract(off)
      double dd = 0.0;
      #pragma unroll
      for (int d = 0; d < 10; ++d){ double df = x[d] - cen[c*10 + d]; double s2 = df*df; dd = dd + s2; }
      if (dd < best){ best = dd; bi = c; }
    }
    label = bi;
  }
  labels[P] = label;
}

// =============== K7: stable counting sort -> member order + offsets ===============
__global__ void k_order(char* ws){ // 1 block x 64 (single wave)
  const int* labels = (const int*)(ws + OFF_LBL);
  int* order = (int*)(ws + OFF_ORD);
  int* offs  = (int*)(ws + OFF_OFFS);
  int t = threadIdx.x;
  __shared__ int cnt[16];
  volatile __shared__ int base[17];
  int my = 0;
  for (int ch = 0; ch < 64; ch++){
    int l = labels[ch*64 + t];
    for (int c = 0; c < 16; c++){
      u64 m = __ballot(l == c);
      if (t == c) my += (int)__popcll(m);
    }
  }
  if (t < 16) cnt[t] = my;
  __syncthreads();
  if (t == 0){
    int a = 0;
    for (int c = 0; c < 16; c++){ base[c] = a; a += cnt[c]; }
    base[16] = a;
    for (int c = 0; c < 17; c++) offs[c] = base[c];
  }
  __syncthreads();
  u64 lower = (t == 0) ? 0ull : ((1ull << t) - 1ull);
  for (int ch = 0; ch < 64; ch++){
    int i = ch*64 + t;
    int l = labels[i];
    for (int c = 0; c < 16; c++){
      u64 m = __ballot(l == c);
      int bc = base[c];                       // read before update (wave in-order)
      if (l == c){ int pos = bc + (int)__popcll(m & lower); order[pos] = i; }
      if (t == c) base[c] = bc + (int)__popcll(m);
    }
  }
}

// =============== K8: qkv = x @ w_in^T + b_in (fp32) ===============
__launch_bounds__(384, 1)
__global__ void k_qkv(const float* __restrict__ x, const float* __restrict__ w_in,
                      const float* __restrict__ b_in, char* ws){
  float* qkv = (float*)(ws + OFF_QKV);
  int b = blockIdx.x, t = threadIdx.x;
  int r0 = b*8;
  __shared__ __align__(16) float xs[8*384];
  for (int idx = t; idx < 8*384; idx += 384) xs[idx] = x[r0*C + idx];
  __syncthreads();
  for (int og = 0; og < 3; og++){
    int o = og*384 + t;
    const float* wr = w_in + (size_t)o*C;
    float acc[8];
    #pragma unroll
    for (int r = 0; r < 8; r++) acc[r] = 0.f;
    for (int k = 0; k < 384; k += 4){
      float4 wv = *(const float4*)(wr + k);
      #pragma unroll
      for (int r = 0; r < 8; r++){
        const float4 xv = *(const float4*)(&xs[r*384 + k]);
        acc[r] += xv.x*wv.x + xv.y*wv.y + xv.z*wv.z + xv.w*wv.w;
      }
    }
    float bias = b_in[o];
    #pragma unroll
    for (int r = 0; r < 8; r++) qkv[(size_t)(r0+r)*C3 + o] = acc[r] + bias;
  }
}

// =============== K9: per-cluster masked attention (online softmax, wave per query) ===============
__launch_bounds__(256, 1)
__global__ void k_cattn(char* ws){
  const float* qkv = (const float*)(ws + OFF_QKV);
  const int* order = (const int*)(ws + OFF_ORD);
  const int* offs  = (const int*)(ws + OFF_OFFS);
  float* attn = (float*)(ws + OFF_ATTN);
  int c = blockIdx.x;
  int w = threadIdx.x >> 6, lane = threadIdx.x & 63;
  int off = offs[c];
  int n = offs[c+1] - off;
  __shared__ __align__(16) float qs[4][384];
  for (int qi = blockIdx.y*4 + w; qi < n; qi += 1024){
    int r = order[off + qi];
    for (int idx = lane; idx < 384; idx += 64) qs[w][idx] = qkv[(size_t)r*C3 + idx];
    __threadfence_block();
    for (int h = 0; h < 8; h++){
      float m = -INFINITY, lsum = 0.f, acc = 0.f;
      const float* qh = &qs[w][h*HD];
      for (int base = 0; base < n; base += 64){
        int j = base + lane;
        int mj = 0; float s = -INFINITY;
        if (j < n){
          mj = order[off + j];
          const float4* kr = (const float4*)(qkv + (size_t)mj*C3 + 384 + h*HD);
          float dot = 0.f;
          #pragma unroll
          for (int q4 = 0; q4 < 12; q4++){
            float4 kv = kr[q4];
            const float4 qv = *(const float4*)(qh + q4*4);
            dot += qv.x*kv.x + qv.y*kv.y + qv.z*kv.z + qv.w*kv.w;
          }
          s = dot / 6.92820323027551f;  // sqrt(48)
        }
        float cm = s;
        #pragma unroll
        for (int d = 32; d >= 1; d >>= 1) cm = fmaxf(cm, __shfl_xor(cm, d));
        float nm = fmaxf(m, cm);
        float alpha = expf(m - nm);
        float p = (j < n) ? expf(s - nm) : 0.f;
        float cs = p;
        #pragma unroll
        for (int d = 32; d >= 1; d >>= 1) cs += __shfl_xor(cs, d);
        lsum = lsum*alpha + cs;
        acc *= alpha;
        int lim = (n - base < 64) ? (n - base) : 64;
        for (int jj = 0; jj < lim; jj++){
          float pv = __shfl(p, jj);
          int mv = __shfl(mj, jj);
          if (lane < 48) acc += pv * qkv[(size_t)mv*C3 + 768 + h*HD + lane];
        }
        m = nm;
      }
      if (lane < 48) attn[(size_t)r*C + h*HD + lane] = acc / lsum;
    }
  }
}

// =============== K10: out-proj + residual + LayerNorm -> h ===============
__launch_bounds__(384, 1)
__global__ void k_outln(const float* __restrict__ x, const float* __restrict__ w_out,
                        const float* __restrict__ b_out, const float* __restrict__ g,
                        const float* __restrict__ bb, char* ws){
  const float* attn = (const float*)(ws + OFF_ATTN);
  float* h = (float*)(ws + OFF_H);
  int b = blockIdx.x, t = threadIdx.x;
  int r0 = b*8;
  __shared__ __align__(16) float as[8*384];
  __shared__ float ov[8*384];
  __shared__ float red[8*48];
  __shared__ float stats[16];
  for (int idx = t; idx < 8*384; idx += 384) as[idx] = attn[(size_t)r0*C + idx];
  __syncthreads();
  const float* wr = w_out + (size_t)t*C;
  float acc[8];
  #pragma unroll
  for (int r = 0; r < 8; r++) acc[r] = 0.f;
  for (int k = 0; k < 384; k += 4){
    float4 wv = *(const float4*)(wr + k);
    #pragma unroll
    for (int r = 0; r < 8; r++){
      const float4 av = *(const float4*)(&as[r*384 + k]);
      acc[r] += av.x*wv.x + av.y*wv.y + av.z*wv.z + av.w*wv.w;
    }
  }
  float bias = b_out[t];
  #pragma unroll
  for (int r = 0; r < 8; r++){
    float v = acc[r] + bias + x[(size_t)(r0+r)*C + t];
    ov[r*384 + t] = v;
  }
  __syncthreads();
  int rr = t & 7, ii = t >> 3;  // 8 rows x 48 partials
  float ps = 0.f;
  for (int j = ii; j < 384; j += 48) ps += ov[rr*384 + j];
  red[rr*48 + ii] = ps; __syncthreads();
  if (t < 8){ float s = 0.f; for (int q = 0; q < 48; q++) s += red[t*48 + q]; stats[t] = s / 384.f; }
  __syncthreads();
  float mu = stats[rr];
  float pv = 0.f;
  for (int j = ii; j < 384; j += 48){ float d = ov[rr*384 + j] - mu; pv += d*d; }
  red[rr*48 + ii] = pv; __syncthreads();
  if (t < 8){ float s = 0.f; for (int q = 0; q < 48; q++) s += red[t*48 + q]; stats[8 + t] = s / 384.f; }
  __syncthreads();
  #pragma unroll
  for (int r = 0; r < 8; r++){
    float mu2 = stats[r], var = stats[8 + r];
    float v = ov[r*384 + t];
    h[(size_t)(r0+r)*C + t] = (v - mu2) / sqrtf(var + 1e-5f) * g[t] + bb[t];
  }
}

// =============== K11: cluster means of h -> reps ===============
__global__ void k_reps(char* ws){ // 16 x 384
  const float* h = (const float*)(ws + OFF_H);
  const int* order = (const int*)(ws + OFF_ORD);
  const int* offs  = (const int*)(ws + OFF_OFFS);
  float* reps = (float*)(ws + OFF_REPS);
  int c = blockIdx.x, t = threadIdx.x;
  int o0 = offs[c], o1 = offs[c+1];
  float acc = 0.f;
  for (int idx = o0; idx < o1; idx++){ int r = order[idx]; acc += h[(size_t)r*C + t]; }
  float cntf = (float)(o1 - o0);
  reps[c*C + t] = acc / fmaxf(cntf, 1.f);
}

// =============== K12: gqkv = reps @ gw_in^T + gb_in ===============
__global__ void k_gqkv(const float* __restrict__ gw_in, const float* __restrict__ gb_in, char* ws){
  const float* reps = (const float*)(ws + OFF_REPS);
  float* gqkv = (float*)(ws + OFF_GQKV);
  int c = blockIdx.x / 3, og = blockIdx.x % 3;
  int t = threadIdx.x;
  __shared__ __align__(16) float rs[384];
  rs[t] = reps[c*C + t]; __syncthreads();
  int o = og*384 + t;
  const float* wr = gw_in + (size_t)o*C;
  float acc = 0.f;
  for (int k = 0; k < 384; k += 4){
    float4 wv = *(const float4*)(wr + k);
    const float4 rv = *(const float4*)(&rs[k]);
    acc += rv.x*wv.x + rv.y*wv.y + rv.z*wv.z + rv.w*wv.w;
  }
  gqkv[c*C3 + o] = acc + gb_in[o];
}

// =============== K13: global attention on reps (16 keys, no mask) ===============
__global__ void k_gattn(char* ws){ // 16 x 64
  const float* gq = (const float*)(ws + OFF_GQKV);
  float* ga = (float*)(ws + OFF_GATT);
  int c = blockIdx.x, lane = threadIdx.x;
  __shared__ float sc[16], pr[16];
  for (int h = 0; h < 8; h++){
    if (lane < 16){
      float dot = 0.f;
      const float* qv = gq + c*C3 + h*HD;
      const float* kv = gq + lane*C3 + 384 + h*HD;
      for (int d = 0; d < 48; d++) dot += qv[d]*kv[d];
      sc[lane] = dot / 6.92820323027551f;
    }
    __threadfence_block();
    if (lane == 0){
      float mx = -INFINITY;
      for (int j = 0; j < 16; j++) mx = fmaxf(mx, sc[j]);
      float sum = 0.f;
      for (int j = 0; j < 16; j++){ float e = expf(sc[j] - mx); pr[j] = e; sum += e; }
      for (int j = 0; j < 16; j++) pr[j] /= sum;
    }
    __threadfence_block();
    if (lane < 48){
      float acc = 0.f;
      for (int j = 0; j < 16; j++) acc += pr[j] * gq[j*C3 + 768 + h*HD + lane];
      ga[c*C + h*HD + lane] = acc;
    }
    __threadfence_block();
  }
}

// =============== K14: global out-proj + residual + LN -> greps ===============
__global__ void k_goutln(const float* __restrict__ gw_out, const float* __restrict__ gb_out,
                         const float* __restrict__ gg, const float* __restrict__ gb2, char* ws){
  const float* ga = (const float*)(ws + OFF_GATT);
  const float* reps = (const float*)(ws + OFF_REPS);
  float* grep = (float*)(ws + OFF_GREP);
  int c = blockIdx.x, t = threadIdx.x; // 384
  __shared__ __align__(16) float as[384];
  __shared__ float ov[384];
  __shared__ float red[64];
  __shared__ float st[2];
  as[t] = ga[c*C + t]; __syncthreads();
  const float* wr = gw_out + (size_t)t*C;
  float acc = 0.f;
  for (int k = 0; k < 384; k += 4){
    float4 wv = *(const float4*)(wr + k);
    const float4 av = *(const float4*)(&as[k]);
    acc += av.x*wv.x + av.y*wv.y + av.z*wv.z + av.w*wv.w;
  }
  float v = acc + gb_out[t] + reps[c*C + t];
  ov[t] = v; __syncthreads();
  if (t < 64){ float s = 0.f; for (int j = t; j < 384; j += 64) s += ov[j]; red[t] = s; }
  __syncthreads();
  if (t == 0){ float s = 0.f; for (int q = 0; q < 64; q++) s += red[q]; st[0] = s / 384.f; }
  __syncthreads();
  float mu = st[0];
  if (t < 64){ float s = 0.f; for (int j = t; j < 384; j += 64){ float d = ov[j]-mu; s += d*d; } red[t] = s; }
  __syncthreads();
  if (t == 0){ float s = 0.f; for (int q = 0; q < 64; q++) s += red[q]; st[1] = s / 384.f; }
  __syncthreads();
  grep[c*C + t] = (v - mu) / sqrtf(st[1] + 1e-5f) * gg[t] + gb2[t];
}

// =============== K15/K16: reps mean + final add ===============
__global__ void k_repmean(char* ws){ // 1 x 384
  const float* grep = (const float*)(ws + OFF_GREP);
  float* rm = (float*)(ws + OFF_RMEAN);
  int t = threadIdx.x;
  float s = 0.f;
  for (int c = 0; c < 16; c++) s += grep[c*C + t];
  rm[t] = s / 16.f;
}

__global__ void k_final(char* ws, float* __restrict__ out){ // 1536 x 256 (float4)
  const float4* h = (const float4*)(ws + OFF_H);
  const float4* rm = (const float4*)(ws + OFF_RMEAN);
  int idx = blockIdx.x*256 + threadIdx.x;
  float4 hv = h[idx];
  float4 rv = rm[idx % 96];
  ((float4*)out)[idx] = make_float4(hv.x + rv.x, hv.y + rv.y, hv.z + rv.z, hv.w + rv.w);
}

// ==================== launcher ====================
extern "C" void kernel_launch(void* const* d_in, const int* in_sizes, int n_in,
                              void* d_out, int out_size, void* d_ws, size_t ws_size,
                              hipStream_t stream){
  (void)in_sizes; (void)n_in; (void)out_size; (void)ws_size;
  const float* x      = (const float*)d_in[0];
  const float* coords = (const float*)d_in[1];
  const float* wp     = (const float*)d_in[2];
  const float* lw_in  = (const float*)d_in[3];
  const float* lb_in  = (const float*)d_in[4];
  const float* lw_out = (const float*)d_in[5];
  const float* lb_out = (const float*)d_in[6];
  const float* lg     = (const float*)d_in[7];
  const float* lb     = (const float*)d_in[8];
  const float* gw_in  = (const float*)d_in[9];
  const float* gb_in  = (const float*)d_in[10];
  const float* gw_out = (const float*)d_in[11];
  const float* gb_out = (const float*)d_in[12];
  const float* gg     = (const float*)d_in[13];
  const float* gb     = (const float*)d_in[14];
  char* ws = (char*)d_ws;

  hipMemsetAsync(ws + OFF_CTRL, 0, AL(CTRL_BYTES), stream);
  hipLaunchKernelGGL(k_colstats,  dim3(25),       dim3(256), 0, stream, x, coords, ws);
  hipLaunchKernelGGL(k_normalize, dim3(4096),     dim3(128), 0, stream, x, coords, ws);
  hipLaunchKernelGGL(k_sigsum,    dim3(512),      dim3(256), 0, stream, ws);
  hipLaunchKernelGGL(k_sigmean,   dim3(1),        dim3(256), 0, stream, ws);
  hipLaunchKernelGGL(k_sigvar,    dim3(512),      dim3(256), 0, stream, ws);
  hipLaunchKernelGGL(k_consts,    dim3(1),        dim3(256), 0, stream, wp, ws);
  hipLaunchKernelGGL(k_simtopk,   dim3(512),      dim3(512), 0, stream, ws);
  hipLaunchKernelGGL(k_kmeans,    dim3(8),        dim3(512), 0, stream, ws);
  hipLaunchKernelGGL(k_order,     dim3(1),        dim3(64),  0, stream, ws);
  hipLaunchKernelGGL(k_qkv,       dim3(512),      dim3(384), 0, stream, x, lw_in, lb_in, ws);
  hipLaunchKernelGGL(k_cattn,     dim3(16, 256),  dim3(256), 0, stream, ws);
  hipLaunchKernelGGL(k_outln,     dim3(512),      dim3(384), 0, stream, x, lw_out, lb_out, lg, lb, ws);
  hipLaunchKernelGGL(k_reps,      dim3(16),       dim3(384), 0, stream, ws);
  hipLaunchKernelGGL(k_gqkv,      dim3(48),       dim3(384), 0, stream, gw_in, gb_in, ws);
  hipLaunchKernelGGL(k_gattn,     dim3(16),       dim3(64),  0, stream, ws);
  hipLaunchKernelGGL(k_goutln,    dim3(16),       dim3(384), 0, stream, gw_out, gb_out, gg, gb, ws);
  hipLaunchKernelGGL(k_repmean,   dim3(1),        dim3(384), 0, stream, ws);
  hipLaunchKernelGGL(k_final,     dim3(1536),     dim3(256), 0, stream, ws, (float*)d_out);
}

// Round 4
// 2771.307 us; speedup vs baseline: 2.1655x; 1.4018x over previous
//
#include <hip/hip_runtime.h>
#include <math.h>
#include <stdint.h>

typedef unsigned long long u64;

// ---------------- problem constants ----------------
constexpr int L  = 4096;
constexpr int C  = 384;
constexpr int C3 = 1152;
constexpr int HD = 48;
constexpr int NCL = 16;
constexpr int KNN = 10;
constexpr int KM_ITERS = 50;

// ---------------- workspace layout (bytes) ----------------
// fz (double[L][C], 12.58MB) is dead before qkv (float[L][C3], 18.87MB) is
// written -> they share one region.
constexpr size_t AL(size_t x){ return (x + 255) & ~size_t(255); }
constexpr size_t OFF_AB    = 0;                                       // union fz/qkv
constexpr size_t OFF_FZ    = OFF_AB;                                  // double [L][C]
constexpr size_t OFF_QKV   = OFF_AB;                                  // float [L][C3]
constexpr size_t OFF_ATTN  = AL(OFF_AB    + sizeof(float)*L*C3);      // float [L][C]
constexpr size_t OFF_H     = AL(OFF_ATTN  + sizeof(float)*L*C);       // float [L][C]
constexpr size_t OFF_CZ    = AL(OFF_H     + sizeof(float)*L*C);       // double [L][2]
constexpr size_t OFF_SQ    = AL(OFF_CZ    + sizeof(double)*L*2);      // double [L]
constexpr size_t OFF_CM    = AL(OFF_SQ    + sizeof(double)*L);        // double [C]
constexpr size_t OFF_CD    = AL(OFF_CM    + sizeof(double)*C);        // double [C]
constexpr size_t OFF_CCM   = AL(OFF_CD    + sizeof(double)*C);        // double [2]
constexpr size_t OFF_CCD   = AL(OFF_CCM   + sizeof(double)*2);        // double [2]
constexpr size_t OFF_SP    = AL(OFF_CCD   + sizeof(double)*2);        // double [512]
constexpr size_t OFF_SP2   = AL(OFF_SP    + sizeof(double)*512);      // double [512]
constexpr size_t OFF_CONST = AL(OFF_SP2   + sizeof(double)*512);      // double [8]: sigma,w0,w1,meandist
constexpr size_t OFF_KNN   = AL(OFF_CONST + sizeof(double)*8);        // double [L][KNN]
constexpr size_t OFF_LBL   = AL(OFF_KNN   + sizeof(double)*L*KNN);    // int [L]
constexpr size_t OFF_ORD   = AL(OFF_LBL   + sizeof(int)*L);           // int [L]
constexpr size_t OFF_OFFS  = AL(OFF_ORD   + sizeof(int)*L);           // int [17]
constexpr size_t OFF_REPS  = AL(OFF_OFFS  + sizeof(int)*32);          // float [16][C]
constexpr size_t OFF_GQKV  = AL(OFF_REPS  + sizeof(float)*NCL*C);     // float [16][C3]
constexpr size_t OFF_GATT  = AL(OFF_GQKV  + sizeof(float)*NCL*C3);    // float [16][C]
constexpr size_t OFF_GREP  = AL(OFF_GATT  + sizeof(float)*NCL*C);     // float [16][C]
constexpr size_t OFF_RMEAN = AL(OFF_GREP  + sizeof(float)*NCL*C);     // float [C]
constexpr size_t OFF_CTRL  = AL(OFF_RMEAN + sizeof(float)*C);         // kmeans control (memset 0)

struct KCtrl {
  u64 sums[3][160];   // int64 fixed-point (2^52) center sums, 3-slot rotation
  int cnt[3][16];
  int chg[3];
  int bar;
};
constexpr size_t CTRL_BYTES = sizeof(KCtrl);
constexpr double FXS = 4503599627370496.0;   // 2^52

#define SCOPE_AGENT __HIP_MEMORY_SCOPE_AGENT

// =============== K1: per-column mean / std(ddof=1), fp64 ===============
__global__ void k_colstats(const float* __restrict__ x, const float* __restrict__ coords, char* ws){
  double* colm = (double*)(ws + OFF_CM);
  double* cold = (double*)(ws + OFF_CD);
  double* ccm  = (double*)(ws + OFF_CCM);
  double* ccd  = (double*)(ws + OFF_CCD);
  int b = blockIdx.x, t = threadIdx.x;
  __shared__ double red[256];
  __shared__ double muS[16];
  if (b < 24) {
    int co = t & 15, rg = t >> 4;
    int col = b*16 + co;
    double s = 0.0;
    for (int r = rg; r < L; r += 16) s += (double)x[r*C + col];
    red[t] = s; __syncthreads();
    for (int w = 8; w >= 1; w >>= 1){ if (rg < w) red[t] += red[t + w*16]; __syncthreads(); }
    if (rg == 0) muS[co] = red[co] / 4096.0;
    __syncthreads();
    double mu = muS[co];
    double ss = 0.0;
    for (int r = rg; r < L; r += 16){ double d = (double)x[r*C + col] - mu; ss += d * d; }
    red[t] = ss; __syncthreads();
    for (int w = 8; w >= 1; w >>= 1){ if (rg < w) red[t] += red[t + w*16]; __syncthreads(); }
    if (rg == 0){ colm[col] = mu; cold[col] = sqrt(red[co] / 4095.0) + 1e-6; }
  } else {
    int co = t & 1, rg = t >> 1;   // 128 row-groups x 2 cols
    double s = 0.0;
    for (int r = rg; r < L; r += 128) s += (double)coords[r*2 + co];
    red[t] = s; __syncthreads();
    for (int w = 64; w >= 1; w >>= 1){ if (rg < w) red[t] += red[t + w*2]; __syncthreads(); }
    if (rg == 0) muS[co] = red[co] / 4096.0;
    __syncthreads();
    double mu = muS[co];
    double ss = 0.0;
    for (int r = rg; r < L; r += 128){ double d = (double)coords[r*2 + co] - mu; ss += d * d; }
    red[t] = ss; __syncthreads();
    for (int w = 64; w >= 1; w >>= 1){ if (rg < w) red[t] += red[t + w*2]; __syncthreads(); }
    if (rg == 0){ ccm[co] = mu; ccd[co] = sqrt(red[co] / 4095.0) + 1e-6; }
  }
}

// =============== K2: fz (z-score + row L2-normalize), cz, sq — fp64 ===============
__global__ void k_normalize(const float* __restrict__ x, const float* __restrict__ coords, char* ws){
  double* fz = (double*)(ws + OFF_FZ);
  double* cz = (double*)(ws + OFF_CZ);
  double* sq = (double*)(ws + OFF_SQ);
  const double* colm = (const double*)(ws + OFF_CM);
  const double* cold = (const double*)(ws + OFF_CD);
  const double* ccm  = (const double*)(ws + OFF_CCM);
  const double* ccd  = (const double*)(ws + OFF_CCD);
  int i = blockIdx.x, t = threadIdx.x; // 128 threads
  double z[3];
  #pragma unroll
  for (int q = 0; q < 3; q++){ int c = t + q*128; z[q] = ((double)x[i*C + c] - colm[c]) / cold[c]; }
  __shared__ double red[128];
  __shared__ double nrmS;
  double s = z[0]*z[0] + z[1]*z[1] + z[2]*z[2];
  red[t] = s; __syncthreads();
  for (int w = 64; w >= 1; w >>= 1){ if (t < w) red[t] += red[t + w]; __syncthreads(); }
  if (t == 0){ double n = sqrt(red[0]); nrmS = n > 1e-12 ? n : 1e-12; }
  __syncthreads();
  double n = nrmS;
  #pragma unroll
  for (int q = 0; q < 3; q++){ int c = t + q*128; fz[(size_t)i*C + c] = z[q] / n; }
  if (t == 0){
    #pragma clang fp contract(off)
    double c0 = ((double)coords[i*2 + 0] - ccm[0]) / ccd[0];
    double c1 = ((double)coords[i*2 + 1] - ccm[1]) / ccd[1];
    cz[i*2 + 0] = c0; cz[i*2 + 1] = c1;
    double p0 = c0*c0; double p1 = c1*c1;
    sq[i] = p0 + p1;
  }
}

// =============== K3a/K3b/K3c/K4: sigma = std(dist, ddof=1), two-pass fp64 ===============
__global__ void k_sigsum(char* ws){
  const double* cz = (const double*)(ws + OFF_CZ);
  const double* sq = (const double*)(ws + OFF_SQ);
  double* sp = (double*)(ws + OFF_SP);
  int b = blockIdx.x, t = threadIdx.x; // 512 x 256
  double s = 0.0;
  const long long total = (long long)L * (long long)L;
  for (long long idx = (long long)b*256 + t; idx < total; idx += (long long)512*256){
    #pragma clang fp contract(off)
    int i = (int)(idx >> 12), j = (int)(idx & 4095);
    double p0 = cz[i*2] * cz[j*2];
    double p1 = cz[i*2+1] * cz[j*2+1];
    double g = p0 + p1;
    double d2 = (sq[i] + sq[j]) - 2.0*g;
    d2 = d2 > 0.0 ? d2 : 0.0;
    s += sqrt(d2);
  }
  __shared__ double r1[256];
  r1[t] = s; __syncthreads();
  for (int w = 128; w >= 1; w >>= 1){ if (t < w) r1[t] += r1[t+w]; __syncthreads(); }
  if (t == 0) sp[b] = r1[0];
}

__global__ void k_sigmean(char* ws){
  const double* sp = (const double*)(ws + OFF_SP);
  double* cst = (double*)(ws + OFF_CONST);
  int t = threadIdx.x; // 256
  __shared__ double r1[256];
  double a = sp[t] + sp[256 + t];
  r1[t] = a; __syncthreads();
  for (int w = 128; w >= 1; w >>= 1){ if (t < w) r1[t] += r1[t+w]; __syncthreads(); }
  if (t == 0) cst[3] = r1[0] / ((double)L * (double)L);
}

__global__ void k_sigvar(char* ws){
  const double* cz = (const double*)(ws + OFF_CZ);
  const double* sq = (const double*)(ws + OFF_SQ);
  const double* cst = (const double*)(ws + OFF_CONST);
  double* sp2 = (double*)(ws + OFF_SP2);
  int b = blockIdx.x, t = threadIdx.x; // 512 x 256
  double mean = cst[3];
  double s = 0.0;
  const long long total = (long long)L * (long long)L;
  for (long long idx = (long long)b*256 + t; idx < total; idx += (long long)512*256){
    #pragma clang fp contract(off)
    int i = (int)(idx >> 12), j = (int)(idx & 4095);
    double p0 = cz[i*2] * cz[j*2];
    double p1 = cz[i*2+1] * cz[j*2+1];
    double g = p0 + p1;
    double d2 = (sq[i] + sq[j]) - 2.0*g;
    d2 = d2 > 0.0 ? d2 : 0.0;
    double d = sqrt(d2) - mean;
    s += d * d;
  }
  __shared__ double r1[256];
  r1[t] = s; __syncthreads();
  for (int w = 128; w >= 1; w >>= 1){ if (t < w) r1[t] += r1[t+w]; __syncthreads(); }
  if (t == 0) sp2[b] = r1[0];
}

__global__ void k_consts(const float* __restrict__ wp, char* ws){
  const double* sp2 = (const double*)(ws + OFF_SP2);
  double* cst = (double*)(ws + OFF_CONST);
  int t = threadIdx.x; // 256
  __shared__ double r1[256];
  double a = sp2[t] + sp2[256 + t];
  r1[t] = a; __syncthreads();
  for (int w = 128; w >= 1; w >>= 1){ if (t < w) r1[t] += r1[t+w]; __syncthreads(); }
  if (t == 0){
    double N = (double)L * (double)L;
    double var = r1[0] / (N - 1.0);
    cst[0] = sqrt(var) + 1e-6;
    double a0 = (double)wp[0], a1 = (double)wp[1];
    double m = a0 > a1 ? a0 : a1;
    double e0 = exp(a0 - m), e1 = exp(a1 - m);
    cst[1] = e0 / (e0 + e1);
    cst[2] = e1 / (e0 + e1);
  }
}

// =============== K5: fused fp64 sim GEMM + per-row top-10 -> knn features ===============
// 8 rows/block, 512 blocks, 512 threads; 8 column passes of 512.
__launch_bounds__(512, 1)
__global__ void k_simtopk(char* ws){
  const double* fz = (const double*)(ws + OFF_FZ);
  const double* cz = (const double*)(ws + OFF_CZ);
  const double* sq = (const double*)(ws + OFF_SQ);
  const double* cst = (const double*)(ws + OFF_CONST);
  double* knn = (double*)(ws + OFF_KNN);
  __shared__ __align__(16) double Afz[8*384];   // 24.6 KB
  __shared__ double simt[8*513];                // 32.8 KB
  __shared__ double Acz[16], Asq[8];
  int t = threadIdx.x;
  int i0 = blockIdx.x * 8;
  for (int idx = t; idx < 8*384; idx += 512) Afz[idx] = fz[(size_t)i0*C + idx];
  if (t < 8){ Asq[t] = sq[i0 + t]; Acz[2*t] = cz[(i0+t)*2]; Acz[2*t+1] = cz[(i0+t)*2+1]; }
  double sigma = cst[0], w0 = cst[1], w1 = cst[2];
  double t10[10];
  #pragma unroll
  for (int q = 0; q < 10; q++) t10[q] = -INFINITY;
  __syncthreads();

  for (int p = 0; p < 8; p++){
    int j = p*512 + t;
    double acc[8];
    #pragma unroll
    for (int r = 0; r < 8; r++) acc[r] = 0.0;
    const double2* bj = (const double2*)(fz + (size_t)j*C);
    for (int k2 = 0; k2 < 192; k2++){
      double2 b = bj[k2];
      #pragma unroll
      for (int r = 0; r < 8; r++){
        const double2 a = *(const double2*)(&Afz[r*384 + k2*2]);
        acc[r] += a.x*b.x + a.y*b.y;
      }
    }
    {
      #pragma clang fp contract(off)
      double cj0 = cz[j*2], cj1 = cz[j*2+1], sj = sq[j];
      for (int r = 0; r < 8; r++){
        double p0 = Acz[2*r]*cj0; double p1 = Acz[2*r+1]*cj1;
        double g = p0 + p1;
        double d2 = (Asq[r] + sj) - 2.0*g;
        d2 = d2 > 0.0 ? d2 : 0.0;
        double dst = sqrt(d2);
        double e = exp(-dst / sigma);
        double u0 = w0*acc[r]; double u1 = w1*e;
        simt[r*513 + t] = u0 + u1;
      }
    }
    __syncthreads();
    if (t < 64){
      int r = t & 7, g = t >> 3;
      const double* row = &simt[r*513 + g*64];
      for (int q = 0; q < 64; q++){
        double v = row[q];
        if (v > t10[9]){
          t10[9] = v;
          #pragma unroll
          for (int u = 9; u >= 1; --u){
            if (t10[u] > t10[u-1]){ double tmp = t10[u-1]; t10[u-1] = t10[u]; t10[u] = tmp; }
          }
        }
      }
    }
    __syncthreads();
  }
  // merge 8 partial lists per row
  if (t < 64){
    int r = t & 7, g = t >> 3;
    #pragma unroll
    for (int q = 0; q < 10; q++) simt[(r*8+g)*10 + q] = t10[q];
  }
  __syncthreads();
  if (t < 8){
    double f10[10];
    #pragma unroll
    for (int q = 0; q < 10; q++) f10[q] = -INFINITY;
    for (int g = 0; g < 8; g++){
      for (int q = 0; q < 10; q++){
        double v = simt[(t*8+g)*10 + q];
        if (v > f10[9]){
          f10[9] = v;
          #pragma unroll
          for (int u = 9; u >= 1; --u){
            if (f10[u] > f10[u-1]){ double tmp = f10[u-1]; f10[u-1] = f10[u]; f10[u] = tmp; }
          }
        }
      }
    }
    double s = 0.0;
    #pragma unroll
    for (int q = 0; q < 10; q++) s += f10[q];
    s = s + 1e-6;
    #pragma unroll
    for (int q = 0; q < 10; q++) knn[(size_t)(i0 + t)*KNN + q] = f10[q] / s;
  }
}

// =============== K6: KMeans fp64 — hierarchical reduction ===============
__device__ __forceinline__ void gbar(int* bar, int target){
  __syncthreads();
  if (threadIdx.x == 0){
    __hip_atomic_fetch_add(bar, 1, __ATOMIC_ACQ_REL, SCOPE_AGENT);
    while (__hip_atomic_load(bar, __ATOMIC_ACQUIRE, SCOPE_AGENT) < target){
      __builtin_amdgcn_s_sleep(1);
    }
  }
  __syncthreads();
}

__launch_bounds__(512, 1)
__global__ void k_kmeans(char* ws){
  const double* knn = (const double*)(ws + OFF_KNN);
  int* labels = (int*)(ws + OFF_LBL);
  KCtrl* ct = (KCtrl*)(ws + OFF_CTRL);
  int t = threadIdx.x, b = blockIdx.x;
  int P = b*512 + t;
  double x[10];
  #pragma unroll
  for (int d = 0; d < 10; d++) x[d] = knn[(size_t)P*KNN + d];
  __shared__ double cen[160];
  __shared__ u64 lsum[160];
  __shared__ int lcnt[16];
  __shared__ int lchg;
  if (t < 160) cen[t] = knn[(size_t)(273*(t/10))*KNN + (t % 10)];  // init_idx[c] = 273*c
  __syncthreads();
  int prev = -1, label = 0;
  int it = 0;
  for (; it < KM_ITERS; ++it){
    if (t < 160) lsum[t] = 0;
    if (t < 16) lcnt[t] = 0;
    if (t == 0) lchg = 0;
    __syncthreads();
    double best = INFINITY; int bi = 0;
    for (int c = 0; c < 16; ++c){
      #pragma clang fp contract(off)
      double dd = 0.0;
      #pragma unroll
      for (int d = 0; d < 10; ++d){ double df = x[d] - cen[c*10 + d]; double s2 = df*df; dd = dd + s2; }
      if (dd < best){ best = dd; bi = c; }
    }
    label = bi;
    #pragma unroll
    for (int d = 0; d < 10; d++){
      long long q = llrint(x[d] * FXS);
      atomicAdd(&lsum[bi*10 + d], (u64)q);
    }
    atomicAdd(&lcnt[bi], 1);
    u64 mb = __ballot(label != prev);
    if (((t & 63) == 0) && mb) atomicAdd(&lchg, (int)__popcll(mb));
    prev = label;
    __syncthreads();
    int slot = it % 3;
    if (t < 160){
      u64 pv = lsum[t];
      if (pv) __hip_atomic_fetch_add(&ct->sums[slot][t], pv, __ATOMIC_RELAXED, SCOPE_AGENT);
    }
    if (t < 16){
      int pc = lcnt[t];
      if (pc) __hip_atomic_fetch_add(&ct->cnt[slot][t], pc, __ATOMIC_RELAXED, SCOPE_AGENT);
    }
    if (t == 0 && lchg) __hip_atomic_fetch_add(&ct->chg[slot], lchg, __ATOMIC_RELAXED, SCOPE_AGENT);
    gbar(&ct->bar, 8*(it+1));
    int chg = __hip_atomic_load(&ct->chg[slot], __ATOMIC_RELAXED, SCOPE_AGENT);
    int zslot = (it + 2) % 3;
    if (t < 160){
      u64 sv = __hip_atomic_load(&ct->sums[slot][t], __ATOMIC_RELAXED, SCOPE_AGENT);
      int cc = __hip_atomic_load(&ct->cnt[slot][t/10], __ATOMIC_RELAXED, SCOPE_AGENT);
      double s = (double)(long long)sv * (1.0 / FXS);
      double cd = (double)cc;
      double nc = s / (cd > 1.0 ? cd : 1.0);
      if (cc > 0) cen[t] = nc;  // else keep old center (reference jnp.where)
      __hip_atomic_store(&ct->sums[zslot][t], (u64)0, __ATOMIC_RELAXED, SCOPE_AGENT);
    }
    if (t < 16) __hip_atomic_store(&ct->cnt[zslot][t], 0, __ATOMIC_RELAXED, SCOPE_AGENT);
    if (t == 0) __hip_atomic_store(&ct->chg[zslot], 0, __ATOMIC_RELAXED, SCOPE_AGENT);
    __syncthreads();
    if (chg == 0) break;  // exact fixed point: remaining iters are bitwise no-ops
  }
  if (it == KM_ITERS){
    double best = INFINITY; int bi = 0;
    for (int c = 0; c < 16; ++c){
      #pragma clang fp contract(off)
      double dd = 0.0;
      #pragma unroll
      for (int d = 0; d < 10; ++d){ double df = x[d] - cen[c*10 + d]; double s2 = df*df; dd = dd + s2; }
      if (dd < best){ best = dd; bi = c; }
    }
    label = bi;
  }
  labels[P] = label;
}

// =============== K7: stable counting sort -> member order + offsets ===============
__global__ void k_order(char* ws){ // 1 block x 64 (single wave)
  const int* labels = (const int*)(ws + OFF_LBL);
  int* order = (int*)(ws + OFF_ORD);
  int* offs  = (int*)(ws + OFF_OFFS);
  int t = threadIdx.x;
  __shared__ int cnt[16];
  volatile __shared__ int base[17];
  int my = 0;
  for (int ch = 0; ch < 64; ch++){
    int l = labels[ch*64 + t];
    for (int c = 0; c < 16; c++){
      u64 m = __ballot(l == c);
      if (t == c) my += (int)__popcll(m);
    }
  }
  if (t < 16) cnt[t] = my;
  __syncthreads();
  if (t == 0){
    int a = 0;
    for (int c = 0; c < 16; c++){ base[c] = a; a += cnt[c]; }
    base[16] = a;
    for (int c = 0; c < 17; c++) offs[c] = base[c];
  }
  __syncthreads();
  u64 lower = (t == 0) ? 0ull : ((1ull << t) - 1ull);
  for (int ch = 0; ch < 64; ch++){
    int i = ch*64 + t;
    int l = labels[i];
    for (int c = 0; c < 16; c++){
      u64 m = __ballot(l == c);
      int bc = base[c];                       // read before update (wave in-order)
      if (l == c){ int pos = bc + (int)__popcll(m & lower); order[pos] = i; }
      if (t == c) base[c] = bc + (int)__popcll(m);
    }
  }
}

// =============== K8: qkv = x @ w_in^T + b_in (fp32) ===============
__launch_bounds__(384, 1)
__global__ void k_qkv(const float* __restrict__ x, const float* __restrict__ w_in,
                      const float* __restrict__ b_in, char* ws){
  float* qkv = (float*)(ws + OFF_QKV);
  int b = blockIdx.x, t = threadIdx.x;
  int r0 = b*8;
  __shared__ __align__(16) float xs[8*384];
  for (int idx = t; idx < 8*384; idx += 384) xs[idx] = x[r0*C + idx];
  __syncthreads();
  for (int og = 0; og < 3; og++){
    int o = og*384 + t;
    const float* wr = w_in + (size_t)o*C;
    float acc[8];
    #pragma unroll
    for (int r = 0; r < 8; r++) acc[r] = 0.f;
    for (int k = 0; k < 384; k += 4){
      float4 wv = *(const float4*)(wr + k);
      #pragma unroll
      for (int r = 0; r < 8; r++){
        const float4 xv = *(const float4*)(&xs[r*384 + k]);
        acc[r] += xv.x*wv.x + xv.y*wv.y + xv.z*wv.z + xv.w*wv.w;
      }
    }
    float bias = b_in[o];
    #pragma unroll
    for (int r = 0; r < 8; r++) qkv[(size_t)(r0+r)*C3 + o] = acc[r] + bias;
  }
}

// =============== K9: per-cluster flash attention, LDS K/V tiles ===============
// grid (16, 64) x 256 thr. Block = (cluster, query-slice); 4 waves = 4 queries.
// Heads outer, K/V tiles of 64 rows staged in LDS (stride 49: <=2-way bank
// alias = free). Same tile order / online softmax as the previous passing
// version -> numerics within fp32 noise.
__launch_bounds__(256, 1)
__global__ void k_cattn(char* ws){
  const float* qkv = (const float*)(ws + OFF_QKV);
  const int* order = (const int*)(ws + OFF_ORD);
  const int* offs  = (const int*)(ws + OFF_OFFS);
  float* attn = (float*)(ws + OFF_ATTN);
  int c = blockIdx.x, yb = blockIdx.y;
  int tid = threadIdx.x;
  int w = tid >> 6, lane = tid & 63;
  int off = offs[c];
  int n = offs[c+1] - off;
  if (yb*4 >= n) return;                 // block-uniform exit
  __shared__ __align__(16) float qs[4][384];
  __shared__ __align__(16) float Kt[64][49];
  __shared__ __align__(16) float Vt[64][49];
  int srow = tid >> 2;                   // staging row 0..63
  int sd0  = (tid & 3) * 12;             // staging dim offset
  for (int q0 = yb*4; q0 < n; q0 += 256){
    int qi = q0 + w;
    bool act = (qi < n);
    int r = 0;
    if (act){
      r = order[off + qi];
      for (int idx = lane; idx < 384; idx += 64) qs[w][idx] = qkv[(size_t)r*C3 + idx];
    }
    for (int h = 0; h < 8; h++){
      float m = -INFINITY, lsum = 0.f, acc = 0.f;
      for (int t0 = 0; t0 < n; t0 += 64){
        int nt = (n - t0 < 64) ? (n - t0) : 64;
        __syncthreads();                 // prior tile reads done
        if (srow < nt){
          int mr = order[off + t0 + srow];
          const float* kp = qkv + (size_t)mr*C3 + 384 + h*HD + sd0;
          const float* vp = qkv + (size_t)mr*C3 + 768 + h*HD + sd0;
          #pragma unroll
          for (int q = 0; q < 12; q += 4){
            *(float4*)&Kt[srow][sd0 + q] = *(const float4*)(kp + q);
            *(float4*)&Vt[srow][sd0 + q] = *(const float4*)(vp + q);
          }
        }
        __syncthreads();
        if (act){
          float s = -INFINITY;
          if (lane < nt){
            const float* qh = &qs[w][h*HD];
            float dot = 0.f;
            #pragma unroll
            for (int d = 0; d < 48; d++) dot += qh[d] * Kt[lane][d];
            s = dot / 6.92820323027551f;  // sqrt(48)
          }
          float cm = s;
          #pragma unroll
          for (int d = 32; d >= 1; d >>= 1) cm = fmaxf(cm, __shfl_xor(cm, d));
          float nm = fmaxf(m, cm);
          float alpha = expf(m - nm);
          float p = (lane < nt) ? expf(s - nm) : 0.f;
          float cs = p;
          #pragma unroll
          for (int d = 32; d >= 1; d >>= 1) cs += __shfl_xor(cs, d);
          lsum = lsum*alpha + cs;
          acc *= alpha;
          for (int jj = 0; jj < nt; jj++){
            float pv = __shfl(p, jj);
            if (lane < 48) acc += pv * Vt[jj][lane];
          }
          m = nm;
        }
      }
      if (act && lane < 48) attn[(size_t)r*C + h*HD + lane] = acc / lsum;
    }
  }
}

// =============== K10: out-proj + residual + LayerNorm -> h ===============
__launch_bounds__(384, 1)
__global__ void k_outln(const float* __restrict__ x, const float* __restrict__ w_out,
                        const float* __restrict__ b_out, const float* __restrict__ g,
                        const float* __restrict__ bb, char* ws){
  const float* attn = (const float*)(ws + OFF_ATTN);
  float* h = (float*)(ws + OFF_H);
  int b = blockIdx.x, t = threadIdx.x;
  int r0 = b*8;
  __shared__ __align__(16) float as[8*384];
  __shared__ float ov[8*384];
  __shared__ float red[8*48];
  __shared__ float stats[16];
  for (int idx = t; idx < 8*384; idx += 384) as[idx] = attn[(size_t)r0*C + idx];
  __syncthreads();
  const float* wr = w_out + (size_t)t*C;
  float acc[8];
  #pragma unroll
  for (int r = 0; r < 8; r++) acc[r] = 0.f;
  for (int k = 0; k < 384; k += 4){
    float4 wv = *(const float4*)(wr + k);
    #pragma unroll
    for (int r = 0; r < 8; r++){
      const float4 av = *(const float4*)(&as[r*384 + k]);
      acc[r] += av.x*wv.x + av.y*wv.y + av.z*wv.z + av.w*wv.w;
    }
  }
  float bias = b_out[t];
  #pragma unroll
  for (int r = 0; r < 8; r++){
    float v = acc[r] + bias + x[(size_t)(r0+r)*C + t];
    ov[r*384 + t] = v;
  }
  __syncthreads();
  int rr = t & 7, ii = t >> 3;  // 8 rows x 48 partials
  float ps = 0.f;
  for (int j = ii; j < 384; j += 48) ps += ov[rr*384 + j];
  red[rr*48 + ii] = ps; __syncthreads();
  if (t < 8){ float s = 0.f; for (int q = 0; q < 48; q++) s += red[t*48 + q]; stats[t] = s / 384.f; }
  __syncthreads();
  float mu = stats[rr];
  float pv = 0.f;
  for (int j = ii; j < 384; j += 48){ float d = ov[rr*384 + j] - mu; pv += d*d; }
  red[rr*48 + ii] = pv; __syncthreads();
  if (t < 8){ float s = 0.f; for (int q = 0; q < 48; q++) s += red[t*48 + q]; stats[8 + t] = s / 384.f; }
  __syncthreads();
  #pragma unroll
  for (int r = 0; r < 8; r++){
    float mu2 = stats[r], var = stats[8 + r];
    float v = ov[r*384 + t];
    h[(size_t)(r0+r)*C + t] = (v - mu2) / sqrtf(var + 1e-5f) * g[t] + bb[t];
  }
}

// =============== K11: cluster means of h -> reps ===============
__global__ void k_reps(char* ws){ // 16 x 384
  const float* h = (const float*)(ws + OFF_H);
  const int* order = (const int*)(ws + OFF_ORD);
  const int* offs  = (const int*)(ws + OFF_OFFS);
  float* reps = (float*)(ws + OFF_REPS);
  int c = blockIdx.x, t = threadIdx.x;
  int o0 = offs[c], o1 = offs[c+1];
  float acc = 0.f;
  for (int idx = o0; idx < o1; idx++){ int r = order[idx]; acc += h[(size_t)r*C + t]; }
  float cntf = (float)(o1 - o0);
  reps[c*C + t] = acc / fmaxf(cntf, 1.f);
}

// =============== K12: gqkv = reps @ gw_in^T + gb_in ===============
__global__ void k_gqkv(const float* __restrict__ gw_in, const float* __restrict__ gb_in, char* ws){
  const float* reps = (const float*)(ws + OFF_REPS);
  float* gqkv = (float*)(ws + OFF_GQKV);
  int c = blockIdx.x / 3, og = blockIdx.x % 3;
  int t = threadIdx.x;
  __shared__ __align__(16) float rs[384];
  rs[t] = reps[c*C + t]; __syncthreads();
  int o = og*384 + t;
  const float* wr = gw_in + (size_t)o*C;
  float acc = 0.f;
  for (int k = 0; k < 384; k += 4){
    float4 wv = *(const float4*)(wr + k);
    const float4 rv = *(const float4*)(&rs[k]);
    acc += rv.x*wv.x + rv.y*wv.y + rv.z*wv.z + rv.w*wv.w;
  }
  gqkv[c*C3 + o] = acc + gb_in[o];
}

// =============== K13: global attention on reps (16 keys, no mask) ===============
__global__ void k_gattn(char* ws){ // 16 x 64
  const float* gq = (const float*)(ws + OFF_GQKV);
  float* ga = (float*)(ws + OFF_GATT);
  int c = blockIdx.x, lane = threadIdx.x;
  __shared__ float sc[16], pr[16];
  for (int h = 0; h < 8; h++){
    if (lane < 16){
      float dot = 0.f;
      const float* qv = gq + c*C3 + h*HD;
      const float* kv = gq + lane*C3 + 384 + h*HD;
      for (int d = 0; d < 48; d++) dot += qv[d]*kv[d];
      sc[lane] = dot / 6.92820323027551f;
    }
    __threadfence_block();
    if (lane == 0){
      float mx = -INFINITY;
      for (int j = 0; j < 16; j++) mx = fmaxf(mx, sc[j]);
      float sum = 0.f;
      for (int j = 0; j < 16; j++){ float e = expf(sc[j] - mx); pr[j] = e; sum += e; }
      for (int j = 0; j < 16; j++) pr[j] /= sum;
    }
    __threadfence_block();
    if (lane < 48){
      float acc = 0.f;
      for (int j = 0; j < 16; j++) acc += pr[j] * gq[j*C3 + 768 + h*HD + lane];
      ga[c*C + h*HD + lane] = acc;
    }
    __threadfence_block();
  }
}

// =============== K14: global out-proj + residual + LN -> greps ===============
__global__ void k_goutln(const float* __restrict__ gw_out, const float* __restrict__ gb_out,
                         const float* __restrict__ gg, const float* __restrict__ gb2, char* ws){
  const float* ga = (const float*)(ws + OFF_GATT);
  const float* reps = (const float*)(ws + OFF_REPS);
  float* grep = (float*)(ws + OFF_GREP);
  int c = blockIdx.x, t = threadIdx.x; // 384
  __shared__ __align__(16) float as[384];
  __shared__ float ov[384];
  __shared__ float red[64];
  __shared__ float st[2];
  as[t] = ga[c*C + t]; __syncthreads();
  const float* wr = gw_out + (size_t)t*C;
  float acc = 0.f;
  for (int k = 0; k < 384; k += 4){
    float4 wv = *(const float4*)(wr + k);
    const float4 av = *(const float4*)(&as[k]);
    acc += av.x*wv.x + av.y*wv.y + av.z*wv.z + av.w*wv.w;
  }
  float v = acc + gb_out[t] + reps[c*C + t];
  ov[t] = v; __syncthreads();
  if (t < 64){ float s = 0.f; for (int j = t; j < 384; j += 64) s += ov[j]; red[t] = s; }
  __syncthreads();
  if (t == 0){ float s = 0.f; for (int q = 0; q < 64; q++) s += red[q]; st[0] = s / 384.f; }
  __syncthreads();
  float mu = st[0];
  if (t < 64){ float s = 0.f; for (int j = t; j < 384; j += 64){ float d = ov[j]-mu; s += d*d; } red[t] = s; }
  __syncthreads();
  if (t == 0){ float s = 0.f; for (int q = 0; q < 64; q++) s += red[q]; st[1] = s / 384.f; }
  __syncthreads();
  grep[c*C + t] = (v - mu) / sqrtf(st[1] + 1e-5f) * gg[t] + gb2[t];
}

// =============== K15/K16: reps mean + final add ===============
__global__ void k_repmean(char* ws){ // 1 x 384
  const float* grep = (const float*)(ws + OFF_GREP);
  float* rm = (float*)(ws + OFF_RMEAN);
  int t = threadIdx.x;
  float s = 0.f;
  for (int c = 0; c < 16; c++) s += grep[c*C + t];
  rm[t] = s / 16.f;
}

__global__ void k_final(char* ws, float* __restrict__ out){ // 1536 x 256 (float4)
  const float4* h = (const float4*)(ws + OFF_H);
  const float4* rm = (const float4*)(ws + OFF_RMEAN);
  int idx = blockIdx.x*256 + threadIdx.x;
  float4 hv = h[idx];
  float4 rv = rm[idx % 96];
  ((float4*)out)[idx] = make_float4(hv.x + rv.x, hv.y + rv.y, hv.z + rv.z, hv.w + rv.w);
}

// ==================== launcher ====================
extern "C" void kernel_launch(void* const* d_in, const int* in_sizes, int n_in,
                              void* d_out, int out_size, void* d_ws, size_t ws_size,
                              hipStream_t stream){
  (void)in_sizes; (void)n_in; (void)out_size; (void)ws_size;
  const float* x      = (const float*)d_in[0];
  const float* coords = (const float*)d_in[1];
  const float* wp     = (const float*)d_in[2];
  const float* lw_in  = (const float*)d_in[3];
  const float* lb_in  = (const float*)d_in[4];
  const float* lw_out = (const float*)d_in[5];
  const float* lb_out = (const float*)d_in[6];
  const float* lg     = (const float*)d_in[7];
  const float* lb     = (const float*)d_in[8];
  const float* gw_in  = (const float*)d_in[9];
  const float* gb_in  = (const float*)d_in[10];
  const float* gw_out = (const float*)d_in[11];
  const float* gb_out = (const float*)d_in[12];
  const float* gg     = (const float*)d_in[13];
  const float* gb     = (const float*)d_in[14];
  char* ws = (char*)d_ws;

  hipMemsetAsync(ws + OFF_CTRL, 0, AL(CTRL_BYTES), stream);
  hipLaunchKernelGGL(k_colstats,  dim3(25),       dim3(256), 0, stream, x, coords, ws);
  hipLaunchKernelGGL(k_normalize, dim3(4096),     dim3(128), 0, stream, x, coords, ws);
  hipLaunchKernelGGL(k_sigsum,    dim3(512),      dim3(256), 0, stream, ws);
  hipLaunchKernelGGL(k_sigmean,   dim3(1),        dim3(256), 0, stream, ws);
  hipLaunchKernelGGL(k_sigvar,    dim3(512),      dim3(256), 0, stream, ws);
  hipLaunchKernelGGL(k_consts,    dim3(1),        dim3(256), 0, stream, wp, ws);
  hipLaunchKernelGGL(k_simtopk,   dim3(512),      dim3(512), 0, stream, ws);
  hipLaunchKernelGGL(k_kmeans,    dim3(8),        dim3(512), 0, stream, ws);
  hipLaunchKernelGGL(k_order,     dim3(1),        dim3(64),  0, stream, ws);
  hipLaunchKernelGGL(k_qkv,       dim3(512),      dim3(384), 0, stream, x, lw_in, lb_in, ws);
  hipLaunchKernelGGL(k_cattn,     dim3(16, 64),   dim3(256), 0, stream, ws);
  hipLaunchKernelGGL(k_outln,     dim3(512),      dim3(384), 0, stream, x, lw_out, lb_out, lg, lb, ws);
  hipLaunchKernelGGL(k_reps,      dim3(16),       dim3(384), 0, stream, ws);
  hipLaunchKernelGGL(k_gqkv,      dim3(48),       dim3(384), 0, stream, gw_in, gb_in, ws);
  hipLaunchKernelGGL(k_gattn,     dim3(16),       dim3(64),  0, stream, ws);
  hipLaunchKernelGGL(k_goutln,    dim3(16),       dim3(384), 0, stream, gw_out, gb_out, gg, gb, ws);
  hipLaunchKernelGGL(k_repmean,   dim3(1),        dim3(384), 0, stream, ws);
  hipLaunchKernelGGL(k_final,     dim3(1536),     dim3(256), 0, stream, ws, (float*)d_out);
}